// Round 10
// baseline (332.345 us; speedup 1.0000x reference)
//
#include <hip/hip_runtime.h>
#include <math.h>

#define IMG 4320
#define H2D 2160
#define FMD 1080
#define FF 21

typedef unsigned short u16;

__device__ __forceinline__ float bf2f(u16 h) {
  return __uint_as_float(((unsigned)h) << 16);
}
__device__ __forceinline__ u16 f2bf(float f) {  // RTNE
  unsigned u = __float_as_uint(f);
  unsigned r = 0x7FFFu + ((u >> 16) & 1u);
  return (u16)((u + r) >> 16);
}

// ============================================================================
// Stage 1a: conv1 (x fp32 -> c1 bf16), 4 rows x 4 cols per thread, batched
// branch-free loads. (256,3): 3 waves/SIMD occupancy experiment.
// ============================================================================
template<bool REDGE>
__device__ __forceinline__ void conv1_body(
    const int gx, const int gy,
    const float* __restrict__ x, const float* __restrict__ w1,
    const float* __restrict__ b1, u16* __restrict__ c1) {
  const int c0 = gx * 4, r0 = gy * 4;
  const bool okL = gx > 0, okR = gx < 1079;
  float s[6][3][6];
  #pragma unroll
  for (int rr = 0; rr < 6; ++rr) {
    const int row = r0 - 1 + rr;
    const int rowc = REDGE ? (row < 0 ? 0 : (row > IMG - 1 ? IMG - 1 : row)) : row;
    const size_t rbase = (size_t)rowc * IMG + c0;
    #pragma unroll
    for (int ic = 0; ic < 3; ++ic) {
      const float* bp = x + (size_t)ic * IMG * IMG + rbase;
      const float4 q = *(const float4*)bp;
      s[rr][ic][1] = q.x; s[rr][ic][2] = q.y; s[rr][ic][3] = q.z; s[rr][ic][4] = q.w;
      s[rr][ic][0] = bp[okL ? -1 : 0];
      s[rr][ic][5] = bp[okR ? 4 : 0];
    }
  }
  #pragma unroll
  for (int rr = 0; rr < 6; ++rr) {
    const bool rok = REDGE ? ((unsigned)(r0 - 1 + rr) < (unsigned)IMG) : true;
    #pragma unroll
    for (int ic = 0; ic < 3; ++ic) {
      if (REDGE) {
        #pragma unroll
        for (int j = 0; j < 6; ++j) s[rr][ic][j] = rok ? s[rr][ic][j] : 0.f;
      }
      s[rr][ic][0] = okL ? s[rr][ic][0] : 0.f;
      s[rr][ic][5] = okR ? s[rr][ic][5] : 0.f;
    }
  }
  float acc[3][4][4];
  #pragma unroll
  for (int oc = 0; oc < 3; ++oc) {
    const float bb = b1[oc];
    #pragma unroll
    for (int r = 0; r < 4; ++r)
      #pragma unroll
      for (int j = 0; j < 4; ++j) acc[oc][r][j] = bb;
  }
  #pragma unroll
  for (int oc = 0; oc < 3; ++oc)
    #pragma unroll
    for (int ic = 0; ic < 3; ++ic)
      #pragma unroll
      for (int dy = 0; dy < 3; ++dy)
        #pragma unroll
        for (int dx = 0; dx < 3; ++dx) {
          const float w = w1[oc * 27 + ic * 9 + dy * 3 + dx];
          #pragma unroll
          for (int r = 0; r < 4; ++r)
            #pragma unroll
            for (int j = 0; j < 4; ++j)
              acc[oc][r][j] += s[r + dy][ic][j + dx] * w;
        }
  #pragma unroll
  for (int oc = 0; oc < 3; ++oc)
    #pragma unroll
    for (int r = 0; r < 4; ++r) {
      ushort4 h;
      h.x = f2bf(acc[oc][r][0]); h.y = f2bf(acc[oc][r][1]);
      h.z = f2bf(acc[oc][r][2]); h.w = f2bf(acc[oc][r][3]);
      *(ushort4*)(c1 + (size_t)oc * IMG * IMG + (size_t)(r0 + r) * IMG + c0) = h;
    }
}

__global__ __launch_bounds__(256, 3) void k_conv1(
    const float* __restrict__ x, const float* __restrict__ w1,
    const float* __restrict__ b1, u16* __restrict__ c1) {
  const int g = blockIdx.x * 256 + threadIdx.x;
  if (g >= 1080 * 1080) return;
  const int gx = g % 1080, gy = g / 1080;
  const int gy_min = (blockIdx.x * 256) / 1080;
  const int gy_max = (blockIdx.x * 256 + 255) / 1080;
  if (gy_min == 0 || gy_max >= 1079) conv1_body<true>(gx, gy, x, w1, b1, c1);
  else                               conv1_body<false>(gx, gy, x, w1, b1, c1);
}

// ============================================================================
// Stage 1b: conv2 + 2x2 maxpool (c1 bf16 -> h2 fp32), 2x2 pooled per thread
// (4 conv rows x 4 conv cols, 6x6 window) — round-8 proven tile, (256,3).
// ============================================================================
template<bool REDGE>
__device__ __forceinline__ void conv2_body(
    const int gx, const int gy,
    const u16* __restrict__ c1, const float* __restrict__ w2,
    const float* __restrict__ b2, float* __restrict__ h2) {
  const int c0 = gx * 4, r0 = gy * 4;
  const bool okL = gx > 0, okR = gx < 1079;
  ushort4 mv[6][3];
  u16 lv[6][3], rv[6][3];
  #pragma unroll
  for (int rr = 0; rr < 6; ++rr) {
    const int row = r0 - 1 + rr;
    const int rowc = REDGE ? (row < 0 ? 0 : (row > IMG - 1 ? IMG - 1 : row)) : row;
    const size_t rbase = (size_t)rowc * IMG + c0;
    #pragma unroll
    for (int ic = 0; ic < 3; ++ic) {
      const u16* bp = c1 + (size_t)ic * IMG * IMG + rbase;
      mv[rr][ic] = *(const ushort4*)bp;
      lv[rr][ic] = bp[okL ? -1 : 0];
      rv[rr][ic] = bp[okR ? 4 : 0];
    }
  }
  float s[6][3][6];
  #pragma unroll
  for (int rr = 0; rr < 6; ++rr) {
    const bool rok = REDGE ? ((unsigned)(r0 - 1 + rr) < (unsigned)IMG) : true;
    #pragma unroll
    for (int ic = 0; ic < 3; ++ic) {
      s[rr][ic][0] = (okL && rok) ? bf2f(lv[rr][ic]) : 0.f;
      s[rr][ic][1] = bf2f(mv[rr][ic].x);
      s[rr][ic][2] = bf2f(mv[rr][ic].y);
      s[rr][ic][3] = bf2f(mv[rr][ic].z);
      s[rr][ic][4] = bf2f(mv[rr][ic].w);
      s[rr][ic][5] = (okR && rok) ? bf2f(rv[rr][ic]) : 0.f;
      if (REDGE) {
        #pragma unroll
        for (int j = 1; j < 5; ++j) s[rr][ic][j] = rok ? s[rr][ic][j] : 0.f;
      }
    }
  }
  float pm[2][2][2];
  #pragma unroll
  for (int oc = 0; oc < 2; ++oc)
    #pragma unroll
    for (int a = 0; a < 2; ++a)
      #pragma unroll
      for (int b = 0; b < 2; ++b) pm[oc][a][b] = -INFINITY;
  #pragma unroll
  for (int cr = 0; cr < 4; ++cr) {
    float v[2][4];
    #pragma unroll
    for (int oc = 0; oc < 2; ++oc) {
      const float bb = b2[oc];
      #pragma unroll
      for (int cc = 0; cc < 4; ++cc) v[oc][cc] = bb;
    }
    #pragma unroll
    for (int oc = 0; oc < 2; ++oc)
      #pragma unroll
      for (int ic = 0; ic < 3; ++ic)
        #pragma unroll
        for (int dy = 0; dy < 3; ++dy)
          #pragma unroll
          for (int dx = 0; dx < 3; ++dx) {
            const float w = w2[oc * 27 + ic * 9 + dy * 3 + dx];
            #pragma unroll
            for (int cc = 0; cc < 4; ++cc)
              v[oc][cc] += s[cr + dy][ic][cc + dx] * w;
          }
    #pragma unroll
    for (int oc = 0; oc < 2; ++oc)
      #pragma unroll
      for (int cc = 0; cc < 4; ++cc)
        pm[oc][cr >> 1][cc >> 1] = fmaxf(pm[oc][cr >> 1][cc >> 1], v[oc][cc]);
  }
  #pragma unroll
  for (int oc = 0; oc < 2; ++oc)
    #pragma unroll
    for (int rp = 0; rp < 2; ++rp) {
      float2 o;
      o.x = pm[oc][rp][0];
      o.y = pm[oc][rp][1];
      *(float2*)(h2 + (size_t)oc * H2D * H2D + (size_t)(gy * 2 + rp) * H2D + gx * 2) = o;
    }
}

__global__ __launch_bounds__(256, 3) void k_conv2pool(
    const u16* __restrict__ c1, const float* __restrict__ w2,
    const float* __restrict__ b2, float* __restrict__ h2) {
  const int g = blockIdx.x * 256 + threadIdx.x;
  if (g >= 1080 * 1080) return;
  const int gx = g % 1080, gy = g / 1080;
  const int gy_min = (blockIdx.x * 256) / 1080;
  const int gy_max = (blockIdx.x * 256 + 255) / 1080;
  if (gy_min == 0 || gy_max >= 1079) conv2_body<true>(gx, gy, c1, w2, b2, h2);
  else                               conv2_body<false>(gx, gy, c1, w2, b2, h2);
}

// ============================================================================
// Stage 2 (FUSED): conv3 -> conv4 -> maxpool2 (h2 -> red [1080,1080]) via LDS
// ============================================================================
__global__ __launch_bounds__(256) void k2_backbone2(
    const float* __restrict__ h2,
    const float* __restrict__ w3, const float* __restrict__ b3,
    const float* __restrict__ w4, const float* __restrict__ b4,
    float* __restrict__ red) {
  __shared__ float hs[2][34][36];
  __shared__ float c3s[2][32][36];
  const int tid = threadIdx.x;
  const int bx = blockIdx.x, by = blockIdx.y;
  const int gy0 = by * 30 - 2, gx0 = bx * 30 - 2;
  float W3[36], B3[2];
  #pragma unroll
  for (int i = 0; i < 36; ++i) W3[i] = w3[i];
  B3[0] = b3[0]; B3[1] = b3[1];
  for (int l = tid; l < 2 * 34 * 34; l += 256) {
    int c = l / 1156, rem = l % 1156, r = rem / 34, cc = rem % 34;
    int gy = gy0 + r, gx = gx0 + cc;
    float v = 0.f;
    if ((unsigned)gy < H2D && (unsigned)gx < H2D)
      v = h2[(size_t)c * H2D * H2D + (size_t)gy * H2D + gx];
    hs[c][r][cc] = v;
  }
  __syncthreads();
  {
    const int r = tid >> 3;
    const int c4 = (tid & 7) << 2;
    float acc[2][4];
    #pragma unroll
    for (int oc = 0; oc < 2; ++oc)
      #pragma unroll
      for (int j = 0; j < 4; ++j) acc[oc][j] = B3[oc];
    #pragma unroll
    for (int ic = 0; ic < 2; ++ic) {
      float xr[3][8];
      #pragma unroll
      for (int dy = 0; dy < 3; ++dy) {
        const float4 q0 = *(const float4*)&hs[ic][r + dy][c4];
        const float4 q1 = *(const float4*)&hs[ic][r + dy][c4 + 4];
        xr[dy][0] = q0.x; xr[dy][1] = q0.y; xr[dy][2] = q0.z; xr[dy][3] = q0.w;
        xr[dy][4] = q1.x; xr[dy][5] = q1.y; xr[dy][6] = q1.z; xr[dy][7] = q1.w;
      }
      #pragma unroll
      for (int oc = 0; oc < 2; ++oc)
        #pragma unroll
        for (int dy = 0; dy < 3; ++dy)
          #pragma unroll
          for (int dx = 0; dx < 3; ++dx) {
            const float w = W3[oc * 18 + ic * 9 + dy * 3 + dx];
            #pragma unroll
            for (int j = 0; j < 4; ++j) acc[oc][j] += xr[dy][j + dx] * w;
          }
    }
    const int gy = by * 30 - 1 + r;
    const bool rOK = (unsigned)gy < H2D;
    const int gxb = bx * 30 - 1 + c4;
    #pragma unroll
    for (int oc = 0; oc < 2; ++oc) {
      float4 o;
      o.x = (rOK && (unsigned)(gxb + 0) < H2D) ? acc[oc][0] : 0.f;
      o.y = (rOK && (unsigned)(gxb + 1) < H2D) ? acc[oc][1] : 0.f;
      o.z = (rOK && (unsigned)(gxb + 2) < H2D) ? acc[oc][2] : 0.f;
      o.w = (rOK && (unsigned)(gxb + 3) < H2D) ? acc[oc][3] : 0.f;
      *(float4*)&c3s[oc][r][c4] = o;
    }
  }
  __syncthreads();
  float W4[18], B4;
  #pragma unroll
  for (int i = 0; i < 18; ++i) W4[i] = w4[i];
  B4 = b4[0];
  const int ty = tid >> 4, tx = tid & 15;
  if (ty < 15 && tx < 15) {
    float cr[2][4][4];
    #pragma unroll
    for (int ic = 0; ic < 2; ++ic)
      #pragma unroll
      for (int rr = 0; rr < 4; ++rr) {
        const float2 p0 = *(const float2*)&c3s[ic][2 * ty + rr][2 * tx];
        const float2 p1 = *(const float2*)&c3s[ic][2 * ty + rr][2 * tx + 2];
        cr[ic][rr][0] = p0.x; cr[ic][rr][1] = p0.y;
        cr[ic][rr][2] = p1.x; cr[ic][rr][3] = p1.y;
      }
    float m = -INFINITY;
    #pragma unroll
    for (int sy = 0; sy < 2; ++sy)
      #pragma unroll
      for (int sx = 0; sx < 2; ++sx) {
        float a = B4;
        #pragma unroll
        for (int ic = 0; ic < 2; ++ic)
          #pragma unroll
          for (int dy = 0; dy < 3; ++dy)
            #pragma unroll
            for (int dx = 0; dx < 3; ++dx)
              a += cr[ic][sy + dy][sx + dx] * W4[ic * 9 + dy * 3 + dx];
        m = fmaxf(m, a);
      }
    red[(size_t)(by * 15 + ty) * FMD + (bx * 15 + tx)] = m;
  }
}

// ============ fallback stage-1 fused kernel (small-ws path) ============
__global__ __launch_bounds__(256) void k1_backbone1(
    const float* __restrict__ x,
    const float* __restrict__ w1, const float* __restrict__ b1,
    const float* __restrict__ w2, const float* __restrict__ b2,
    float* __restrict__ h2) {
  __shared__ float xs[3][34][36];
  __shared__ float c1s[3][32][36];
  const int tid = threadIdx.x;
  const int bx = blockIdx.x, by = blockIdx.y;
  const int gy0 = by * 30 - 2, gx0 = bx * 30 - 2;
  float W1[81], B1[3];
  #pragma unroll
  for (int i = 0; i < 81; ++i) W1[i] = w1[i];
  #pragma unroll
  for (int i = 0; i < 3; ++i) B1[i] = b1[i];
  for (int l = tid; l < 3 * 34 * 34; l += 256) {
    int c = l / 1156, rem = l % 1156, r = rem / 34, cc = rem % 34;
    int gy = gy0 + r, gx = gx0 + cc;
    float v = 0.f;
    if ((unsigned)gy < IMG && (unsigned)gx < IMG)
      v = x[(size_t)c * IMG * IMG + (size_t)gy * IMG + gx];
    xs[c][r][cc] = v;
  }
  __syncthreads();
  {
    const int r = tid >> 3;
    const int c4 = (tid & 7) << 2;
    float acc[3][4];
    #pragma unroll
    for (int oc = 0; oc < 3; ++oc)
      #pragma unroll
      for (int j = 0; j < 4; ++j) acc[oc][j] = B1[oc];
    #pragma unroll
    for (int ic = 0; ic < 3; ++ic) {
      float xr[3][8];
      #pragma unroll
      for (int dy = 0; dy < 3; ++dy) {
        const float4 q0 = *(const float4*)&xs[ic][r + dy][c4];
        const float4 q1 = *(const float4*)&xs[ic][r + dy][c4 + 4];
        xr[dy][0] = q0.x; xr[dy][1] = q0.y; xr[dy][2] = q0.z; xr[dy][3] = q0.w;
        xr[dy][4] = q1.x; xr[dy][5] = q1.y; xr[dy][6] = q1.z; xr[dy][7] = q1.w;
      }
      #pragma unroll
      for (int oc = 0; oc < 3; ++oc)
        #pragma unroll
        for (int dy = 0; dy < 3; ++dy)
          #pragma unroll
          for (int dx = 0; dx < 3; ++dx) {
            const float w = W1[oc * 27 + ic * 9 + dy * 3 + dx];
            #pragma unroll
            for (int j = 0; j < 4; ++j) acc[oc][j] += xr[dy][j + dx] * w;
          }
    }
    const int gy = by * 30 - 1 + r;
    const bool rOK = (unsigned)gy < IMG;
    const int gxb = bx * 30 - 1 + c4;
    #pragma unroll
    for (int oc = 0; oc < 3; ++oc) {
      float4 o;
      o.x = (rOK && (unsigned)(gxb + 0) < IMG) ? acc[oc][0] : 0.f;
      o.y = (rOK && (unsigned)(gxb + 1) < IMG) ? acc[oc][1] : 0.f;
      o.z = (rOK && (unsigned)(gxb + 2) < IMG) ? acc[oc][2] : 0.f;
      o.w = (rOK && (unsigned)(gxb + 3) < IMG) ? acc[oc][3] : 0.f;
      *(float4*)&c1s[oc][r][c4] = o;
    }
  }
  __syncthreads();
  float W2[54], B2[2];
  #pragma unroll
  for (int i = 0; i < 54; ++i) W2[i] = w2[i];
  B2[0] = b2[0]; B2[1] = b2[1];
  const int ty = tid >> 4, tx = tid & 15;
  if (ty < 15 && tx < 15) {
    float cr[3][4][4];
    #pragma unroll
    for (int ic = 0; ic < 3; ++ic)
      #pragma unroll
      for (int rr = 0; rr < 4; ++rr) {
        const float2 p0 = *(const float2*)&c1s[ic][2 * ty + rr][2 * tx];
        const float2 p1 = *(const float2*)&c1s[ic][2 * ty + rr][2 * tx + 2];
        cr[ic][rr][0] = p0.x; cr[ic][rr][1] = p0.y;
        cr[ic][rr][2] = p1.x; cr[ic][rr][3] = p1.y;
      }
    float m0 = -INFINITY, m1 = -INFINITY;
    #pragma unroll
    for (int sy = 0; sy < 2; ++sy)
      #pragma unroll
      for (int sx = 0; sx < 2; ++sx) {
        float a0 = B2[0], a1 = B2[1];
        #pragma unroll
        for (int ic = 0; ic < 3; ++ic)
          #pragma unroll
          for (int dy = 0; dy < 3; ++dy)
            #pragma unroll
            for (int dx = 0; dx < 3; ++dx) {
              const float v = cr[ic][sy + dy][sx + dx];
              a0 += v * W2[ic * 9 + dy * 3 + dx];
              a1 += v * W2[27 + ic * 9 + dy * 3 + dx];
            }
        m0 = fmaxf(m0, a0);
        m1 = fmaxf(m1, a1);
      }
    const size_t o = (size_t)(by * 15 + ty) * H2D + (bx * 15 + tx);
    h2[o] = m0;
    h2[(size_t)H2D * H2D + o] = m1;
  }
}

// ============ K3: rpn_conv (50x50, stride 50)  (reduced -> y [2,21,21]) ============
__global__ __launch_bounds__(256) void k3_rpnconv(
    const float* __restrict__ red,
    const float* __restrict__ w, const float* __restrict__ b,
    float* __restrict__ y) {
  __shared__ float part[256];
  const int cell = blockIdx.x;
  const int i = cell / FF, j = cell % FF;
  const int tid = threadIdx.x;
  float a0 = 0.f, a1 = 0.f;
  for (int t = tid; t < 2500; t += 256) {
    int ay = t / 50, ax = t % 50;
    float v = red[(size_t)(50 * i + ay) * FMD + 50 * j + ax];
    a0 += v * w[t];
    a1 += v * w[2500 + t];
  }
  part[tid] = a0;
  __syncthreads();
  for (int s = 128; s > 0; s >>= 1) {
    if (tid < s) part[tid] += part[tid + s];
    __syncthreads();
  }
  if (tid == 0) y[cell] = part[0] + b[0];
  __syncthreads();
  part[tid] = a1;
  __syncthreads();
  for (int s = 128; s > 0; s >>= 1) {
    if (tid < s) part[tid] += part[tid + s];
    __syncthreads();
  }
  if (tid == 0) y[441 + cell] = part[0] + b[1];
}

// ============ K4: rpn heads + faithful masked-select + proposals/rects ============
__global__ __launch_bounds__(512) void k4_select(
    const float* __restrict__ y,
    const float* __restrict__ bbw, const float* __restrict__ bbb,
    const float* __restrict__ clw, const float* __restrict__ clb,
    float* __restrict__ props_out, int* __restrict__ rects,
    unsigned* __restrict__ pooled_m) {
  __shared__ float ys[2][23][23];
  __shared__ unsigned char flag[6][441];
  __shared__ short pos[6][20];
  __shared__ int cnt[6];
  __shared__ int selT[20];
  __shared__ float offv[20], anchv[20];
  const int tid = threadIdx.x;
  for (int l = tid; l < 2 * 23 * 23; l += 512) ((float*)ys)[l] = 0.f;
  __syncthreads();
  for (int l = tid; l < 2 * 441; l += 512) {
    int c = l / 441, p = l % 441;
    ys[c][p / 21 + 1][p % 21 + 1] = y[l];
  }
  __syncthreads();
  for (int l = tid; l < 6 * 441; l += 512) {
    int a = l / 441, p = l % 441, i = p / 21, j = p % 21;
    float v = clb[a];
    #pragma unroll
    for (int c2 = 0; c2 < 2; c2++)
      #pragma unroll
      for (int dy = 0; dy < 3; dy++)
        #pragma unroll
        for (int dx = 0; dx < 3; dx++)
          v += ys[c2][i + dy][j + dx] * clw[a * 18 + c2 * 9 + dy * 3 + dx];
    flag[a][p] = (tanhf(v) > 0.95f) ? 1 : 0;
  }
  __syncthreads();
  if (tid < 6) {
    int c = 0;
    for (int p = 0; p < 441; p++)
      if (flag[tid][p]) {
        if (c < 20) pos[tid][c] = (short)p;
        c++;
      }
    cnt[tid] = c;
  }
  __syncthreads();
  if (tid == 0) {
    int s = 0;
    for (int g = 0; g < 24 && s < 20; g++) {
      int a = g >> 2;
      int take = cnt[a] < 20 - s ? cnt[a] : 20 - s;
      for (int r = 0; r < take; r++) selT[s++] = g * 441 + (int)pos[a][r];
    }
    if (s < 20) {
      for (int t = 0; t < 10584 && s < 20; t++) {
        int a = t / 1764, p = t % 441;
        if (!flag[a][p]) selT[s++] = t;
      }
    }
  }
  __syncthreads();
  if (tid < 20) {
    int t = selT[tid];
    int ch = t / 441, p = t % 441, i = p / 21, j = p % 21;
    int a = ch >> 2, c = ch & 3;
    float v = bbb[ch];
    #pragma unroll
    for (int c2 = 0; c2 < 2; c2++)
      #pragma unroll
      for (int dy = 0; dy < 3; dy++)
        #pragma unroll
        for (int dx = 0; dx < 3; dx++)
          v += ys[c2][i + dy][j + dx] * bbw[ch * 18 + c2 * 9 + dy * 3 + dx];
    offv[tid] = v;
    float sz = (a < 3) ? 1.f : 2.f;
    int am = a % 3;
    float ar = (am == 0) ? 0.5f : (am == 1 ? 1.f : 2.f);
    float base;
    if (c == 0) base = 0.f;
    else if (c == 1) base = sz * -(ar - 1.f) * 0.5f;
    else if (c == 2) base = sz;
    else base = sz * (1.f + (ar - 1.f) * 0.5f);
    anchv[tid] = base + ((c & 1) ? (float)j : (float)i);
  }
  __syncthreads();
  if (tid < 5) {
    int k = tid;
    float o0 = offv[4 * k], o1 = offv[4 * k + 1], o2 = offv[4 * k + 2], o3 = offv[4 * k + 3];
    float a0 = anchv[4 * k], a2 = anchv[4 * k + 2], a3 = anchv[4 * k + 3];
    float p0 = fminf(fmaxf(o0 + a0 - a2 * 0.5f, 0.f), 21.f) * 50.f;
    float p1 = fminf(fmaxf(o1 - a3 * 0.5f, 0.f), 21.f) * 50.f;
    float p2 = fminf(fmaxf(o2 + a0 + a2 * 0.5f, 0.f), 21.f) * 50.f;
    float p3 = fminf(fmaxf(o3 + a3 * 0.5f, 0.f), 21.f) * 50.f;
    props_out[k * 4 + 0] = p0;
    props_out[k * 4 + 1] = p1;
    props_out[k * 4 + 2] = p2;
    props_out[k * 4 + 3] = p3;
    float x1 = rintf(p0), y1 = rintf(p1), x2 = rintf(p2), y2 = rintf(p3);
    float bwf = fmaxf(x2 - x1 + 1.f, 1.f) * 0.5f;
    float bhf = fmaxf(y2 - y1 + 1.f, 1.f) * 0.5f;
    for (int ph = 0; ph < 2; ph++)
      for (int pw = 0; pw < 2; pw++) {
        int hsv = (int)fminf(fmaxf(floorf((float)ph * bhf) + y1, 0.f), 1080.f);
        int hev = (int)fminf(fmaxf(ceilf((float)(ph + 1) * bhf) + y1, 0.f), 1080.f);
        int wsv = (int)fminf(fmaxf(floorf((float)pw * bwf) + x1, 0.f), 1080.f);
        int wev = (int)fminf(fmaxf(ceilf((float)(pw + 1) * bwf) + x1, 0.f), 1080.f);
        int idx = k * 4 + ph * 2 + pw;
        rects[idx * 4 + 0] = hsv;
        rects[idx * 4 + 1] = hev;
        rects[idx * 4 + 2] = wsv;
        rects[idx * 4 + 3] = wev;
      }
  }
  if (tid >= 32 && tid < 52) pooled_m[tid - 32] = 0x007FFFFFu;  // mapped(-inf)
}

// ============ K5: RoI max pool (atomicMax on order-preserving uint map) ============
__global__ __launch_bounds__(256) void k5_roipool(
    const float* __restrict__ red, const int* __restrict__ rects,
    unsigned* __restrict__ pooled_m) {
  const int cell = blockIdx.x;
  const int hs = rects[cell * 4 + 0], he = rects[cell * 4 + 1];
  const int wss = rects[cell * 4 + 2], wee = rects[cell * 4 + 3];
  const int nr = he - hs;
  if (nr <= 0 || wee <= wss) return;
  const int slice = blockIdx.y, nslice = gridDim.y;
  const int r0 = hs + (int)((long)nr * slice / nslice);
  const int r1 = hs + (int)((long)nr * (slice + 1) / nslice);
  float m = -INFINITY;
  for (int r = r0; r < r1; r++)
    for (int c = wss + (int)threadIdx.x; c < wee; c += 256)
      m = fmaxf(m, red[(size_t)r * FMD + c]);
  __shared__ float part[256];
  part[threadIdx.x] = m;
  __syncthreads();
  for (int s = 128; s > 0; s >>= 1) {
    if ((int)threadIdx.x < s) part[threadIdx.x] = fmaxf(part[threadIdx.x], part[threadIdx.x + s]);
    __syncthreads();
  }
  if (threadIdx.x == 0 && part[0] > -INFINITY) {
    unsigned u = __float_as_uint(part[0]);
    u = (u & 0x80000000u) ? ~u : (u | 0x80000000u);
    atomicMax(&pooled_m[cell], u);
  }
}

// ============ K6: fc / box / cls heads -> d_out (30 floats) ============
__global__ void k6_heads(
    const unsigned* __restrict__ pooled_m, const float* __restrict__ props,
    const float* __restrict__ fcw, const float* __restrict__ fcb,
    const float* __restrict__ bxw, const float* __restrict__ bxb,
    const float* __restrict__ clw, const float* __restrict__ clb,
    float* __restrict__ out) {
  if (threadIdx.x != 0 || blockIdx.x != 0) return;
  float pooled[5][4];
  for (int i = 0; i < 20; i++) {
    unsigned u = pooled_m[i];
    float f = (u & 0x80000000u) ? __uint_as_float(u ^ 0x80000000u) : __uint_as_float(~u);
    if (!isfinite(f)) f = 0.f;
    pooled[i / 4][i % 4] = f;
  }
  for (int k = 0; k < 5; k++) {
    float fc[12];
    for (int m = 0; m < 12; m++) {
      float v = fcb[m];
      for (int n = 0; n < 4; n++) v += pooled[k][n] * fcw[m * 4 + n];
      fc[m] = v;
    }
    float bo[4];
    for (int c = 0; c < 4; c++) {
      float v = bxb[c];
      for (int m = 0; m < 12; m++) v += fc[m] * bxw[c * 12 + m];
      bo[c] = v;
    }
    float p0 = props[k * 4], p1 = props[k * 4 + 1], p2 = props[k * 4 + 2], p3 = props[k * 4 + 3];
    out[k * 4 + 0] = fminf(fmaxf(p0 + bo[0] - bo[2] * 0.5f, 0.f), 3.f);
    out[k * 4 + 1] = fminf(fmaxf(p1 - bo[3] * 0.5f, 0.f), 1.f);
    out[k * 4 + 2] = fminf(fmaxf(p2 + bo[0] + bo[2] * 0.5f, 0.f), 3.f);
    out[k * 4 + 3] = fminf(fmaxf(p3 + bo[3] * 0.5f, 0.f), 1.f);
    float l0 = clb[0], l1 = clb[1];
    for (int m = 0; m < 12; m++) {
      l0 += fc[m] * clw[m];
      l1 += fc[m] * clw[12 + m];
    }
    float mx = fmaxf(l0, l1);
    float e0 = expf(l0 - mx), e1 = expf(l1 - mx);
    out[20 + k * 2 + 0] = e0 / (e0 + e1);
    out[20 + k * 2 + 1] = e1 / (e0 + e1);
  }
}

extern "C" void kernel_launch(void* const* d_in, const int* in_sizes, int n_in,
                              void* d_out, int out_size, void* d_ws, size_t ws_size,
                              hipStream_t stream) {
  const float* x   = (const float*)d_in[0];
  const float* w1  = (const float*)d_in[1];
  const float* b1  = (const float*)d_in[2];
  const float* w2  = (const float*)d_in[3];
  const float* b2  = (const float*)d_in[4];
  const float* w3  = (const float*)d_in[5];
  const float* b3  = (const float*)d_in[6];
  const float* w4  = (const float*)d_in[7];
  const float* b4  = (const float*)d_in[8];
  const float* rw  = (const float*)d_in[9];
  const float* rb  = (const float*)d_in[10];
  const float* bbw = (const float*)d_in[11];
  const float* bbb = (const float*)d_in[12];
  const float* clw = (const float*)d_in[13];
  const float* clb = (const float*)d_in[14];
  const float* fcw = (const float*)d_in[15];
  const float* fcb = (const float*)d_in[16];
  const float* bxw = (const float*)d_in[17];
  const float* bxb = (const float*)d_in[18];
  const float* c2w = (const float*)d_in[19];
  const float* c2b = (const float*)d_in[20];

  char* wsb = (char*)d_ws;

  if (ws_size >= 160000000ull) {
    // split path: c1(bf16) | h2 | red | small
    u16*   c1u = (u16*)wsb;
    float* h2  = (float*)(wsb + 111974400);
    float* red = (float*)(wsb + 149299200);
    float* yv  = (float*)(wsb + 153964800);
    float* props = yv + 882;
    int*   rects = (int*)(props + 20);
    unsigned* pooled_m = (unsigned*)(rects + 80);

    k_conv1    <<<4557, 256, 0, stream>>>(x, w1, b1, c1u);
    k_conv2pool<<<4557, 256, 0, stream>>>(c1u, w2, b2, h2);
    k2_backbone2<<<dim3(72, 72), 256, 0, stream>>>(h2, w3, b3, w4, b4, red);
    k3_rpnconv<<<441, 256, 0, stream>>>(red, rw, rb, yv);
    k4_select<<<1, 512, 0, stream>>>(yv, bbw, bbb, clw, clb, props, rects, pooled_m);
    k5_roipool<<<dim3(20, 16), 256, 0, stream>>>(red, rects, pooled_m);
    k6_heads<<<1, 64, 0, stream>>>(pooled_m, props, fcw, fcb, bxw, bxb, c2w, c2b,
                                   (float*)d_out);
  } else {
    // fallback: round-2 fused path (42 MB workspace)
    float* ws = (float*)d_ws;
    float* h2 = ws;
    float* red = ws + 9331200;
    float* yv = ws + 10497600;
    float* props = ws + 10498482;
    int* rects = (int*)(ws + 10498502);
    unsigned* pooled_m = (unsigned*)(ws + 10498582);

    k1_backbone1<<<dim3(144, 144), 256, 0, stream>>>(x, w1, b1, w2, b2, h2);
    k2_backbone2<<<dim3(72, 72), 256, 0, stream>>>(h2, w3, b3, w4, b4, red);
    k3_rpnconv<<<441, 256, 0, stream>>>(red, rw, rb, yv);
    k4_select<<<1, 512, 0, stream>>>(yv, bbw, bbb, clw, clb, props, rects, pooled_m);
    k5_roipool<<<dim3(20, 16), 256, 0, stream>>>(red, rects, pooled_m);
    k6_heads<<<1, 64, 0, stream>>>(pooled_m, props, fcw, fcb, bxw, bxb, c2w, c2b,
                                   (float*)d_out);
  }
}

// Round 11
// 219.788 us; speedup vs baseline: 1.5121x; 1.5121x over previous
//
#include <hip/hip_runtime.h>
#include <math.h>

#define IMG 4320
#define H2D 2160
#define FMD 1080
#define FF 21

typedef unsigned short u16;

__device__ __forceinline__ float bf2f(u16 h) {
  return __uint_as_float(((unsigned)h) << 16);
}
__device__ __forceinline__ u16 f2bf(float f) {  // RTNE
  unsigned u = __float_as_uint(f);
  unsigned r = 0x7FFFu + ((u >> 16) & 1u);
  return (u16)((u + r) >> 16);
}

// ============================================================================
// Stage 1a: conv1 (x fp32 -> c1 bf16), 4 rows x 4 cols per thread, batched
// branch-free loads, (256,2) -> VGPR cap 256, no spill.  [round-8 proven]
// ============================================================================
template<bool REDGE>
__device__ __forceinline__ void conv1_body(
    const int gx, const int gy,
    const float* __restrict__ x, const float* __restrict__ w1,
    const float* __restrict__ b1, u16* __restrict__ c1) {
  const int c0 = gx * 4, r0 = gy * 4;
  const bool okL = gx > 0, okR = gx < 1079;
  float s[6][3][6];
  #pragma unroll
  for (int rr = 0; rr < 6; ++rr) {
    const int row = r0 - 1 + rr;
    const int rowc = REDGE ? (row < 0 ? 0 : (row > IMG - 1 ? IMG - 1 : row)) : row;
    const size_t rbase = (size_t)rowc * IMG + c0;
    #pragma unroll
    for (int ic = 0; ic < 3; ++ic) {
      const float* bp = x + (size_t)ic * IMG * IMG + rbase;
      const float4 q = *(const float4*)bp;
      s[rr][ic][1] = q.x; s[rr][ic][2] = q.y; s[rr][ic][3] = q.z; s[rr][ic][4] = q.w;
      s[rr][ic][0] = bp[okL ? -1 : 0];
      s[rr][ic][5] = bp[okR ? 4 : 0];
    }
  }
  #pragma unroll
  for (int rr = 0; rr < 6; ++rr) {
    const bool rok = REDGE ? ((unsigned)(r0 - 1 + rr) < (unsigned)IMG) : true;
    #pragma unroll
    for (int ic = 0; ic < 3; ++ic) {
      if (REDGE) {
        #pragma unroll
        for (int j = 0; j < 6; ++j) s[rr][ic][j] = rok ? s[rr][ic][j] : 0.f;
      }
      s[rr][ic][0] = okL ? s[rr][ic][0] : 0.f;
      s[rr][ic][5] = okR ? s[rr][ic][5] : 0.f;
    }
  }
  float acc[3][4][4];
  #pragma unroll
  for (int oc = 0; oc < 3; ++oc) {
    const float bb = b1[oc];
    #pragma unroll
    for (int r = 0; r < 4; ++r)
      #pragma unroll
      for (int j = 0; j < 4; ++j) acc[oc][r][j] = bb;
  }
  #pragma unroll
  for (int oc = 0; oc < 3; ++oc)
    #pragma unroll
    for (int ic = 0; ic < 3; ++ic)
      #pragma unroll
      for (int dy = 0; dy < 3; ++dy)
        #pragma unroll
        for (int dx = 0; dx < 3; ++dx) {
          const float w = w1[oc * 27 + ic * 9 + dy * 3 + dx];
          #pragma unroll
          for (int r = 0; r < 4; ++r)
            #pragma unroll
            for (int j = 0; j < 4; ++j)
              acc[oc][r][j] += s[r + dy][ic][j + dx] * w;
        }
  #pragma unroll
  for (int oc = 0; oc < 3; ++oc)
    #pragma unroll
    for (int r = 0; r < 4; ++r) {
      ushort4 h;
      h.x = f2bf(acc[oc][r][0]); h.y = f2bf(acc[oc][r][1]);
      h.z = f2bf(acc[oc][r][2]); h.w = f2bf(acc[oc][r][3]);
      *(ushort4*)(c1 + (size_t)oc * IMG * IMG + (size_t)(r0 + r) * IMG + c0) = h;
    }
}

__global__ __launch_bounds__(256, 2) void k_conv1(
    const float* __restrict__ x, const float* __restrict__ w1,
    const float* __restrict__ b1, u16* __restrict__ c1) {
  const int g = blockIdx.x * 256 + threadIdx.x;
  if (g >= 1080 * 1080) return;
  const int gx = g % 1080, gy = g / 1080;
  const int gy_min = (blockIdx.x * 256) / 1080;
  const int gy_max = (blockIdx.x * 256 + 255) / 1080;
  if (gy_min == 0 || gy_max >= 1079) conv1_body<true>(gx, gy, x, w1, b1, c1);
  else                               conv1_body<false>(gx, gy, x, w1, b1, c1);
}

// ============================================================================
// Stage 1b: conv2 + 2x2 maxpool (c1 bf16 -> h2 fp32), 2x2 pooled per thread
// (4 conv rows x 4 conv cols, 6x6 window), (256,2).  [round-8 proven]
// ============================================================================
template<bool REDGE>
__device__ __forceinline__ void conv2_body(
    const int gx, const int gy,
    const u16* __restrict__ c1, const float* __restrict__ w2,
    const float* __restrict__ b2, float* __restrict__ h2) {
  const int c0 = gx * 4, r0 = gy * 4;
  const bool okL = gx > 0, okR = gx < 1079;
  ushort4 mv[6][3];
  u16 lv[6][3], rv[6][3];
  #pragma unroll
  for (int rr = 0; rr < 6; ++rr) {
    const int row = r0 - 1 + rr;
    const int rowc = REDGE ? (row < 0 ? 0 : (row > IMG - 1 ? IMG - 1 : row)) : row;
    const size_t rbase = (size_t)rowc * IMG + c0;
    #pragma unroll
    for (int ic = 0; ic < 3; ++ic) {
      const u16* bp = c1 + (size_t)ic * IMG * IMG + rbase;
      mv[rr][ic] = *(const ushort4*)bp;
      lv[rr][ic] = bp[okL ? -1 : 0];
      rv[rr][ic] = bp[okR ? 4 : 0];
    }
  }
  float s[6][3][6];
  #pragma unroll
  for (int rr = 0; rr < 6; ++rr) {
    const bool rok = REDGE ? ((unsigned)(r0 - 1 + rr) < (unsigned)IMG) : true;
    #pragma unroll
    for (int ic = 0; ic < 3; ++ic) {
      s[rr][ic][0] = (okL && rok) ? bf2f(lv[rr][ic]) : 0.f;
      s[rr][ic][1] = bf2f(mv[rr][ic].x);
      s[rr][ic][2] = bf2f(mv[rr][ic].y);
      s[rr][ic][3] = bf2f(mv[rr][ic].z);
      s[rr][ic][4] = bf2f(mv[rr][ic].w);
      s[rr][ic][5] = (okR && rok) ? bf2f(rv[rr][ic]) : 0.f;
      if (REDGE) {
        #pragma unroll
        for (int j = 1; j < 5; ++j) s[rr][ic][j] = rok ? s[rr][ic][j] : 0.f;
      }
    }
  }
  float pm[2][2][2];
  #pragma unroll
  for (int oc = 0; oc < 2; ++oc)
    #pragma unroll
    for (int a = 0; a < 2; ++a)
      #pragma unroll
      for (int b = 0; b < 2; ++b) pm[oc][a][b] = -INFINITY;
  #pragma unroll
  for (int cr = 0; cr < 4; ++cr) {
    float v[2][4];
    #pragma unroll
    for (int oc = 0; oc < 2; ++oc) {
      const float bb = b2[oc];
      #pragma unroll
      for (int cc = 0; cc < 4; ++cc) v[oc][cc] = bb;
    }
    #pragma unroll
    for (int oc = 0; oc < 2; ++oc)
      #pragma unroll
      for (int ic = 0; ic < 3; ++ic)
        #pragma unroll
        for (int dy = 0; dy < 3; ++dy)
          #pragma unroll
          for (int dx = 0; dx < 3; ++dx) {
            const float w = w2[oc * 27 + ic * 9 + dy * 3 + dx];
            #pragma unroll
            for (int cc = 0; cc < 4; ++cc)
              v[oc][cc] += s[cr + dy][ic][cc + dx] * w;
          }
    #pragma unroll
    for (int oc = 0; oc < 2; ++oc)
      #pragma unroll
      for (int cc = 0; cc < 4; ++cc)
        pm[oc][cr >> 1][cc >> 1] = fmaxf(pm[oc][cr >> 1][cc >> 1], v[oc][cc]);
  }
  #pragma unroll
  for (int oc = 0; oc < 2; ++oc)
    #pragma unroll
    for (int rp = 0; rp < 2; ++rp) {
      float2 o;
      o.x = pm[oc][rp][0];
      o.y = pm[oc][rp][1];
      *(float2*)(h2 + (size_t)oc * H2D * H2D + (size_t)(gy * 2 + rp) * H2D + gx * 2) = o;
    }
}

__global__ __launch_bounds__(256, 2) void k_conv2pool(
    const u16* __restrict__ c1, const float* __restrict__ w2,
    const float* __restrict__ b2, float* __restrict__ h2) {
  const int g = blockIdx.x * 256 + threadIdx.x;
  if (g >= 1080 * 1080) return;
  const int gx = g % 1080, gy = g / 1080;
  const int gy_min = (blockIdx.x * 256) / 1080;
  const int gy_max = (blockIdx.x * 256 + 255) / 1080;
  if (gy_min == 0 || gy_max >= 1079) conv2_body<true>(gx, gy, c1, w2, b2, h2);
  else                               conv2_body<false>(gx, gy, c1, w2, b2, h2);
}

// ============================================================================
// Stage 2 (FUSED): conv3 -> conv4 -> maxpool2 (h2 -> red [1080,1080]) via LDS
// ============================================================================
__global__ __launch_bounds__(256) void k2_backbone2(
    const float* __restrict__ h2,
    const float* __restrict__ w3, const float* __restrict__ b3,
    const float* __restrict__ w4, const float* __restrict__ b4,
    float* __restrict__ red) {
  __shared__ float hs[2][34][36];
  __shared__ float c3s[2][32][36];
  const int tid = threadIdx.x;
  const int bx = blockIdx.x, by = blockIdx.y;
  const int gy0 = by * 30 - 2, gx0 = bx * 30 - 2;
  float W3[36], B3[2];
  #pragma unroll
  for (int i = 0; i < 36; ++i) W3[i] = w3[i];
  B3[0] = b3[0]; B3[1] = b3[1];
  for (int l = tid; l < 2 * 34 * 34; l += 256) {
    int c = l / 1156, rem = l % 1156, r = rem / 34, cc = rem % 34;
    int gy = gy0 + r, gx = gx0 + cc;
    float v = 0.f;
    if ((unsigned)gy < H2D && (unsigned)gx < H2D)
      v = h2[(size_t)c * H2D * H2D + (size_t)gy * H2D + gx];
    hs[c][r][cc] = v;
  }
  __syncthreads();
  {
    const int r = tid >> 3;
    const int c4 = (tid & 7) << 2;
    float acc[2][4];
    #pragma unroll
    for (int oc = 0; oc < 2; ++oc)
      #pragma unroll
      for (int j = 0; j < 4; ++j) acc[oc][j] = B3[oc];
    #pragma unroll
    for (int ic = 0; ic < 2; ++ic) {
      float xr[3][8];
      #pragma unroll
      for (int dy = 0; dy < 3; ++dy) {
        const float4 q0 = *(const float4*)&hs[ic][r + dy][c4];
        const float4 q1 = *(const float4*)&hs[ic][r + dy][c4 + 4];
        xr[dy][0] = q0.x; xr[dy][1] = q0.y; xr[dy][2] = q0.z; xr[dy][3] = q0.w;
        xr[dy][4] = q1.x; xr[dy][5] = q1.y; xr[dy][6] = q1.z; xr[dy][7] = q1.w;
      }
      #pragma unroll
      for (int oc = 0; oc < 2; ++oc)
        #pragma unroll
        for (int dy = 0; dy < 3; ++dy)
          #pragma unroll
          for (int dx = 0; dx < 3; ++dx) {
            const float w = W3[oc * 18 + ic * 9 + dy * 3 + dx];
            #pragma unroll
            for (int j = 0; j < 4; ++j) acc[oc][j] += xr[dy][j + dx] * w;
          }
    }
    const int gy = by * 30 - 1 + r;
    const bool rOK = (unsigned)gy < H2D;
    const int gxb = bx * 30 - 1 + c4;
    #pragma unroll
    for (int oc = 0; oc < 2; ++oc) {
      float4 o;
      o.x = (rOK && (unsigned)(gxb + 0) < H2D) ? acc[oc][0] : 0.f;
      o.y = (rOK && (unsigned)(gxb + 1) < H2D) ? acc[oc][1] : 0.f;
      o.z = (rOK && (unsigned)(gxb + 2) < H2D) ? acc[oc][2] : 0.f;
      o.w = (rOK && (unsigned)(gxb + 3) < H2D) ? acc[oc][3] : 0.f;
      *(float4*)&c3s[oc][r][c4] = o;
    }
  }
  __syncthreads();
  float W4[18], B4;
  #pragma unroll
  for (int i = 0; i < 18; ++i) W4[i] = w4[i];
  B4 = b4[0];
  const int ty = tid >> 4, tx = tid & 15;
  if (ty < 15 && tx < 15) {
    float cr[2][4][4];
    #pragma unroll
    for (int ic = 0; ic < 2; ++ic)
      #pragma unroll
      for (int rr = 0; rr < 4; ++rr) {
        const float2 p0 = *(const float2*)&c3s[ic][2 * ty + rr][2 * tx];
        const float2 p1 = *(const float2*)&c3s[ic][2 * ty + rr][2 * tx + 2];
        cr[ic][rr][0] = p0.x; cr[ic][rr][1] = p0.y;
        cr[ic][rr][2] = p1.x; cr[ic][rr][3] = p1.y;
      }
    float m = -INFINITY;
    #pragma unroll
    for (int sy = 0; sy < 2; ++sy)
      #pragma unroll
      for (int sx = 0; sx < 2; ++sx) {
        float a = B4;
        #pragma unroll
        for (int ic = 0; ic < 2; ++ic)
          #pragma unroll
          for (int dy = 0; dy < 3; ++dy)
            #pragma unroll
            for (int dx = 0; dx < 3; ++dx)
              a += cr[ic][sy + dy][sx + dx] * W4[ic * 9 + dy * 3 + dx];
        m = fmaxf(m, a);
      }
    red[(size_t)(by * 15 + ty) * FMD + (bx * 15 + tx)] = m;
  }
}

// ============ fallback stage-1 fused kernel (small-ws path) ============
__global__ __launch_bounds__(256) void k1_backbone1(
    const float* __restrict__ x,
    const float* __restrict__ w1, const float* __restrict__ b1,
    const float* __restrict__ w2, const float* __restrict__ b2,
    float* __restrict__ h2) {
  __shared__ float xs[3][34][36];
  __shared__ float c1s[3][32][36];
  const int tid = threadIdx.x;
  const int bx = blockIdx.x, by = blockIdx.y;
  const int gy0 = by * 30 - 2, gx0 = bx * 30 - 2;
  float W1[81], B1[3];
  #pragma unroll
  for (int i = 0; i < 81; ++i) W1[i] = w1[i];
  #pragma unroll
  for (int i = 0; i < 3; ++i) B1[i] = b1[i];
  for (int l = tid; l < 3 * 34 * 34; l += 256) {
    int c = l / 1156, rem = l % 1156, r = rem / 34, cc = rem % 34;
    int gy = gy0 + r, gx = gx0 + cc;
    float v = 0.f;
    if ((unsigned)gy < IMG && (unsigned)gx < IMG)
      v = x[(size_t)c * IMG * IMG + (size_t)gy * IMG + gx];
    xs[c][r][cc] = v;
  }
  __syncthreads();
  {
    const int r = tid >> 3;
    const int c4 = (tid & 7) << 2;
    float acc[3][4];
    #pragma unroll
    for (int oc = 0; oc < 3; ++oc)
      #pragma unroll
      for (int j = 0; j < 4; ++j) acc[oc][j] = B1[oc];
    #pragma unroll
    for (int ic = 0; ic < 3; ++ic) {
      float xr[3][8];
      #pragma unroll
      for (int dy = 0; dy < 3; ++dy) {
        const float4 q0 = *(const float4*)&xs[ic][r + dy][c4];
        const float4 q1 = *(const float4*)&xs[ic][r + dy][c4 + 4];
        xr[dy][0] = q0.x; xr[dy][1] = q0.y; xr[dy][2] = q0.z; xr[dy][3] = q0.w;
        xr[dy][4] = q1.x; xr[dy][5] = q1.y; xr[dy][6] = q1.z; xr[dy][7] = q1.w;
      }
      #pragma unroll
      for (int oc = 0; oc < 3; ++oc)
        #pragma unroll
        for (int dy = 0; dy < 3; ++dy)
          #pragma unroll
          for (int dx = 0; dx < 3; ++dx) {
            const float w = W1[oc * 27 + ic * 9 + dy * 3 + dx];
            #pragma unroll
            for (int j = 0; j < 4; ++j) acc[oc][j] += xr[dy][j + dx] * w;
          }
    }
    const int gy = by * 30 - 1 + r;
    const bool rOK = (unsigned)gy < IMG;
    const int gxb = bx * 30 - 1 + c4;
    #pragma unroll
    for (int oc = 0; oc < 3; ++oc) {
      float4 o;
      o.x = (rOK && (unsigned)(gxb + 0) < IMG) ? acc[oc][0] : 0.f;
      o.y = (rOK && (unsigned)(gxb + 1) < IMG) ? acc[oc][1] : 0.f;
      o.z = (rOK && (unsigned)(gxb + 2) < IMG) ? acc[oc][2] : 0.f;
      o.w = (rOK && (unsigned)(gxb + 3) < IMG) ? acc[oc][3] : 0.f;
      *(float4*)&c1s[oc][r][c4] = o;
    }
  }
  __syncthreads();
  float W2[54], B2[2];
  #pragma unroll
  for (int i = 0; i < 54; ++i) W2[i] = w2[i];
  B2[0] = b2[0]; B2[1] = b2[1];
  const int ty = tid >> 4, tx = tid & 15;
  if (ty < 15 && tx < 15) {
    float cr[3][4][4];
    #pragma unroll
    for (int ic = 0; ic < 3; ++ic)
      #pragma unroll
      for (int rr = 0; rr < 4; ++rr) {
        const float2 p0 = *(const float2*)&c1s[ic][2 * ty + rr][2 * tx];
        const float2 p1 = *(const float2*)&c1s[ic][2 * ty + rr][2 * tx + 2];
        cr[ic][rr][0] = p0.x; cr[ic][rr][1] = p0.y;
        cr[ic][rr][2] = p1.x; cr[ic][rr][3] = p1.y;
      }
    float m0 = -INFINITY, m1 = -INFINITY;
    #pragma unroll
    for (int sy = 0; sy < 2; ++sy)
      #pragma unroll
      for (int sx = 0; sx < 2; ++sx) {
        float a0 = B2[0], a1 = B2[1];
        #pragma unroll
        for (int ic = 0; ic < 3; ++ic)
          #pragma unroll
          for (int dy = 0; dy < 3; ++dy)
            #pragma unroll
            for (int dx = 0; dx < 3; ++dx) {
              const float v = cr[ic][sy + dy][sx + dx];
              a0 += v * W2[ic * 9 + dy * 3 + dx];
              a1 += v * W2[27 + ic * 9 + dy * 3 + dx];
            }
        m0 = fmaxf(m0, a0);
        m1 = fmaxf(m1, a1);
      }
    const size_t o = (size_t)(by * 15 + ty) * H2D + (bx * 15 + tx);
    h2[o] = m0;
    h2[(size_t)H2D * H2D + o] = m1;
  }
}

// ============ K3: rpn_conv (50x50, stride 50)  (reduced -> y [2,21,21]) ============
__global__ __launch_bounds__(256) void k3_rpnconv(
    const float* __restrict__ red,
    const float* __restrict__ w, const float* __restrict__ b,
    float* __restrict__ y) {
  __shared__ float part[256];
  const int cell = blockIdx.x;
  const int i = cell / FF, j = cell % FF;
  const int tid = threadIdx.x;
  float a0 = 0.f, a1 = 0.f;
  for (int t = tid; t < 2500; t += 256) {
    int ay = t / 50, ax = t % 50;
    float v = red[(size_t)(50 * i + ay) * FMD + 50 * j + ax];
    a0 += v * w[t];
    a1 += v * w[2500 + t];
  }
  part[tid] = a0;
  __syncthreads();
  for (int s = 128; s > 0; s >>= 1) {
    if (tid < s) part[tid] += part[tid + s];
    __syncthreads();
  }
  if (tid == 0) y[cell] = part[0] + b[0];
  __syncthreads();
  part[tid] = a1;
  __syncthreads();
  for (int s = 128; s > 0; s >>= 1) {
    if (tid < s) part[tid] += part[tid + s];
    __syncthreads();
  }
  if (tid == 0) y[441 + cell] = part[0] + b[1];
}

// ============ K4: rpn heads + faithful masked-select + proposals/rects ============
__global__ __launch_bounds__(512) void k4_select(
    const float* __restrict__ y,
    const float* __restrict__ bbw, const float* __restrict__ bbb,
    const float* __restrict__ clw, const float* __restrict__ clb,
    float* __restrict__ props_out, int* __restrict__ rects,
    unsigned* __restrict__ pooled_m) {
  __shared__ float ys[2][23][23];
  __shared__ unsigned char flag[6][441];
  __shared__ short pos[6][20];
  __shared__ int cnt[6];
  __shared__ int selT[20];
  __shared__ float offv[20], anchv[20];
  const int tid = threadIdx.x;
  for (int l = tid; l < 2 * 23 * 23; l += 512) ((float*)ys)[l] = 0.f;
  __syncthreads();
  for (int l = tid; l < 2 * 441; l += 512) {
    int c = l / 441, p = l % 441;
    ys[c][p / 21 + 1][p % 21 + 1] = y[l];
  }
  __syncthreads();
  for (int l = tid; l < 6 * 441; l += 512) {
    int a = l / 441, p = l % 441, i = p / 21, j = p % 21;
    float v = clb[a];
    #pragma unroll
    for (int c2 = 0; c2 < 2; c2++)
      #pragma unroll
      for (int dy = 0; dy < 3; dy++)
        #pragma unroll
        for (int dx = 0; dx < 3; dx++)
          v += ys[c2][i + dy][j + dx] * clw[a * 18 + c2 * 9 + dy * 3 + dx];
    flag[a][p] = (tanhf(v) > 0.95f) ? 1 : 0;
  }
  __syncthreads();
  if (tid < 6) {
    int c = 0;
    for (int p = 0; p < 441; p++)
      if (flag[tid][p]) {
        if (c < 20) pos[tid][c] = (short)p;
        c++;
      }
    cnt[tid] = c;
  }
  __syncthreads();
  if (tid == 0) {
    int s = 0;
    for (int g = 0; g < 24 && s < 20; g++) {
      int a = g >> 2;
      int take = cnt[a] < 20 - s ? cnt[a] : 20 - s;
      for (int r = 0; r < take; r++) selT[s++] = g * 441 + (int)pos[a][r];
    }
    if (s < 20) {
      for (int t = 0; t < 10584 && s < 20; t++) {
        int a = t / 1764, p = t % 441;
        if (!flag[a][p]) selT[s++] = t;
      }
    }
  }
  __syncthreads();
  if (tid < 20) {
    int t = selT[tid];
    int ch = t / 441, p = t % 441, i = p / 21, j = p % 21;
    int a = ch >> 2, c = ch & 3;
    float v = bbb[ch];
    #pragma unroll
    for (int c2 = 0; c2 < 2; c2++)
      #pragma unroll
      for (int dy = 0; dy < 3; dy++)
        #pragma unroll
        for (int dx = 0; dx < 3; dx++)
          v += ys[c2][i + dy][j + dx] * bbw[ch * 18 + c2 * 9 + dy * 3 + dx];
    offv[tid] = v;
    float sz = (a < 3) ? 1.f : 2.f;
    int am = a % 3;
    float ar = (am == 0) ? 0.5f : (am == 1 ? 1.f : 2.f);
    float base;
    if (c == 0) base = 0.f;
    else if (c == 1) base = sz * -(ar - 1.f) * 0.5f;
    else if (c == 2) base = sz;
    else base = sz * (1.f + (ar - 1.f) * 0.5f);
    anchv[tid] = base + ((c & 1) ? (float)j : (float)i);
  }
  __syncthreads();
  if (tid < 5) {
    int k = tid;
    float o0 = offv[4 * k], o1 = offv[4 * k + 1], o2 = offv[4 * k + 2], o3 = offv[4 * k + 3];
    float a0 = anchv[4 * k], a2 = anchv[4 * k + 2], a3 = anchv[4 * k + 3];
    float p0 = fminf(fmaxf(o0 + a0 - a2 * 0.5f, 0.f), 21.f) * 50.f;
    float p1 = fminf(fmaxf(o1 - a3 * 0.5f, 0.f), 21.f) * 50.f;
    float p2 = fminf(fmaxf(o2 + a0 + a2 * 0.5f, 0.f), 21.f) * 50.f;
    float p3 = fminf(fmaxf(o3 + a3 * 0.5f, 0.f), 21.f) * 50.f;
    props_out[k * 4 + 0] = p0;
    props_out[k * 4 + 1] = p1;
    props_out[k * 4 + 2] = p2;
    props_out[k * 4 + 3] = p3;
    float x1 = rintf(p0), y1 = rintf(p1), x2 = rintf(p2), y2 = rintf(p3);
    float bwf = fmaxf(x2 - x1 + 1.f, 1.f) * 0.5f;
    float bhf = fmaxf(y2 - y1 + 1.f, 1.f) * 0.5f;
    for (int ph = 0; ph < 2; ph++)
      for (int pw = 0; pw < 2; pw++) {
        int hsv = (int)fminf(fmaxf(floorf((float)ph * bhf) + y1, 0.f), 1080.f);
        int hev = (int)fminf(fmaxf(ceilf((float)(ph + 1) * bhf) + y1, 0.f), 1080.f);
        int wsv = (int)fminf(fmaxf(floorf((float)pw * bwf) + x1, 0.f), 1080.f);
        int wev = (int)fminf(fmaxf(ceilf((float)(pw + 1) * bwf) + x1, 0.f), 1080.f);
        int idx = k * 4 + ph * 2 + pw;
        rects[idx * 4 + 0] = hsv;
        rects[idx * 4 + 1] = hev;
        rects[idx * 4 + 2] = wsv;
        rects[idx * 4 + 3] = wev;
      }
  }
  if (tid >= 32 && tid < 52) pooled_m[tid - 32] = 0x007FFFFFu;  // mapped(-inf)
}

// ============ K5: RoI max pool (atomicMax on order-preserving uint map) ============
__global__ __launch_bounds__(256) void k5_roipool(
    const float* __restrict__ red, const int* __restrict__ rects,
    unsigned* __restrict__ pooled_m) {
  const int cell = blockIdx.x;
  const int hs = rects[cell * 4 + 0], he = rects[cell * 4 + 1];
  const int wss = rects[cell * 4 + 2], wee = rects[cell * 4 + 3];
  const int nr = he - hs;
  if (nr <= 0 || wee <= wss) return;
  const int slice = blockIdx.y, nslice = gridDim.y;
  const int r0 = hs + (int)((long)nr * slice / nslice);
  const int r1 = hs + (int)((long)nr * (slice + 1) / nslice);
  float m = -INFINITY;
  for (int r = r0; r < r1; r++)
    for (int c = wss + (int)threadIdx.x; c < wee; c += 256)
      m = fmaxf(m, red[(size_t)r * FMD + c]);
  __shared__ float part[256];
  part[threadIdx.x] = m;
  __syncthreads();
  for (int s = 128; s > 0; s >>= 1) {
    if ((int)threadIdx.x < s) part[threadIdx.x] = fmaxf(part[threadIdx.x], part[threadIdx.x + s]);
    __syncthreads();
  }
  if (threadIdx.x == 0 && part[0] > -INFINITY) {
    unsigned u = __float_as_uint(part[0]);
    u = (u & 0x80000000u) ? ~u : (u | 0x80000000u);
    atomicMax(&pooled_m[cell], u);
  }
}

// ============ K6: fc / box / cls heads -> d_out (30 floats) ============
__global__ void k6_heads(
    const unsigned* __restrict__ pooled_m, const float* __restrict__ props,
    const float* __restrict__ fcw, const float* __restrict__ fcb,
    const float* __restrict__ bxw, const float* __restrict__ bxb,
    const float* __restrict__ clw, const float* __restrict__ clb,
    float* __restrict__ out) {
  if (threadIdx.x != 0 || blockIdx.x != 0) return;
  float pooled[5][4];
  for (int i = 0; i < 20; i++) {
    unsigned u = pooled_m[i];
    float f = (u & 0x80000000u) ? __uint_as_float(u ^ 0x80000000u) : __uint_as_float(~u);
    if (!isfinite(f)) f = 0.f;
    pooled[i / 4][i % 4] = f;
  }
  for (int k = 0; k < 5; k++) {
    float fc[12];
    for (int m = 0; m < 12; m++) {
      float v = fcb[m];
      for (int n = 0; n < 4; n++) v += pooled[k][n] * fcw[m * 4 + n];
      fc[m] = v;
    }
    float bo[4];
    for (int c = 0; c < 4; c++) {
      float v = bxb[c];
      for (int m = 0; m < 12; m++) v += fc[m] * bxw[c * 12 + m];
      bo[c] = v;
    }
    float p0 = props[k * 4], p1 = props[k * 4 + 1], p2 = props[k * 4 + 2], p3 = props[k * 4 + 3];
    out[k * 4 + 0] = fminf(fmaxf(p0 + bo[0] - bo[2] * 0.5f, 0.f), 3.f);
    out[k * 4 + 1] = fminf(fmaxf(p1 - bo[3] * 0.5f, 0.f), 1.f);
    out[k * 4 + 2] = fminf(fmaxf(p2 + bo[0] + bo[2] * 0.5f, 0.f), 3.f);
    out[k * 4 + 3] = fminf(fmaxf(p3 + bo[3] * 0.5f, 0.f), 1.f);
    float l0 = clb[0], l1 = clb[1];
    for (int m = 0; m < 12; m++) {
      l0 += fc[m] * clw[m];
      l1 += fc[m] * clw[12 + m];
    }
    float mx = fmaxf(l0, l1);
    float e0 = expf(l0 - mx), e1 = expf(l1 - mx);
    out[20 + k * 2 + 0] = e0 / (e0 + e1);
    out[20 + k * 2 + 1] = e1 / (e0 + e1);
  }
}

extern "C" void kernel_launch(void* const* d_in, const int* in_sizes, int n_in,
                              void* d_out, int out_size, void* d_ws, size_t ws_size,
                              hipStream_t stream) {
  const float* x   = (const float*)d_in[0];
  const float* w1  = (const float*)d_in[1];
  const float* b1  = (const float*)d_in[2];
  const float* w2  = (const float*)d_in[3];
  const float* b2  = (const float*)d_in[4];
  const float* w3  = (const float*)d_in[5];
  const float* b3  = (const float*)d_in[6];
  const float* w4  = (const float*)d_in[7];
  const float* b4  = (const float*)d_in[8];
  const float* rw  = (const float*)d_in[9];
  const float* rb  = (const float*)d_in[10];
  const float* bbw = (const float*)d_in[11];
  const float* bbb = (const float*)d_in[12];
  const float* clw = (const float*)d_in[13];
  const float* clb = (const float*)d_in[14];
  const float* fcw = (const float*)d_in[15];
  const float* fcb = (const float*)d_in[16];
  const float* bxw = (const float*)d_in[17];
  const float* bxb = (const float*)d_in[18];
  const float* c2w = (const float*)d_in[19];
  const float* c2b = (const float*)d_in[20];

  char* wsb = (char*)d_ws;

  if (ws_size >= 160000000ull) {
    // split path: c1(bf16) | h2 | red | small
    u16*   c1u = (u16*)wsb;
    float* h2  = (float*)(wsb + 111974400);
    float* red = (float*)(wsb + 149299200);
    float* yv  = (float*)(wsb + 153964800);
    float* props = yv + 882;
    int*   rects = (int*)(props + 20);
    unsigned* pooled_m = (unsigned*)(rects + 80);

    k_conv1    <<<4557, 256, 0, stream>>>(x, w1, b1, c1u);
    k_conv2pool<<<4557, 256, 0, stream>>>(c1u, w2, b2, h2);
    k2_backbone2<<<dim3(72, 72), 256, 0, stream>>>(h2, w3, b3, w4, b4, red);
    k3_rpnconv<<<441, 256, 0, stream>>>(red, rw, rb, yv);
    k4_select<<<1, 512, 0, stream>>>(yv, bbw, bbb, clw, clb, props, rects, pooled_m);
    k5_roipool<<<dim3(20, 16), 256, 0, stream>>>(red, rects, pooled_m);
    k6_heads<<<1, 64, 0, stream>>>(pooled_m, props, fcw, fcb, bxw, bxb, c2w, c2b,
                                   (float*)d_out);
  } else {
    // fallback: round-2 fused path (42 MB workspace)
    float* ws = (float*)d_ws;
    float* h2 = ws;
    float* red = ws + 9331200;
    float* yv = ws + 10497600;
    float* props = ws + 10498482;
    int* rects = (int*)(ws + 10498502);
    unsigned* pooled_m = (unsigned*)(ws + 10498582);

    k1_backbone1<<<dim3(144, 144), 256, 0, stream>>>(x, w1, b1, w2, b2, h2);
    k2_backbone2<<<dim3(72, 72), 256, 0, stream>>>(h2, w3, b3, w4, b4, red);
    k3_rpnconv<<<441, 256, 0, stream>>>(red, rw, rb, yv);
    k4_select<<<1, 512, 0, stream>>>(yv, bbw, bbb, clw, clb, props, rects, pooled_m);
    k5_roipool<<<dim3(20, 16), 256, 0, stream>>>(red, rects, pooled_m);
    k6_heads<<<1, 64, 0, stream>>>(pooled_m, props, fcw, fcb, bxw, bxb, c2w, c2b,
                                   (float*)d_out);
  }
}

// Round 12
// 210.455 us; speedup vs baseline: 1.5792x; 1.0443x over previous
//
#include <hip/hip_runtime.h>
#include <math.h>

#define IMG 4320
#define H2D 2160
#define FMD 1080
#define FF 21

typedef unsigned short u16;

__device__ __forceinline__ float bf2f(u16 h) {
  return __uint_as_float(((unsigned)h) << 16);
}
__device__ __forceinline__ u16 f2bf(float f) {  // RTNE
  unsigned u = __float_as_uint(f);
  unsigned r = 0x7FFFu + ((u >> 16) & 1u);
  return (u16)((u + r) >> 16);
}

// ============================================================================
// Stage 1a: conv1 (x fp32 -> c1 bf16), 4 rows x 4 cols per thread.
// Halo columns via __shfl from neighbor lanes' float4 loads; wave-edge
// fixups via ONE gathered masked load (lanes 0-17 left, 32-49 right).
// vmem instructions per thread: 18 float4 + 1 gather (was 54).
// ============================================================================
template<bool REDGE>
__device__ __forceinline__ void conv1_body(
    const int g, const int gx, const int gy,
    const float* __restrict__ x, const float* __restrict__ w1,
    const float* __restrict__ b1, u16* __restrict__ c1) {
  const int lane = threadIdx.x & 63;
  const int c0 = gx * 4, r0 = gy * 4;
  const bool okL = gx > 0, okR = gx < 1079;

  // wave-uniform geometry of lane0 / lane63 for halo gather
  const int g0 = __builtin_amdgcn_readfirstlane(g - lane);
  const int g63 = g0 + 63;
  const int gx0w = g0 % 1080, gy0w = g0 / 1080;
  const int gx63w = g63 % 1080, gy63w = g63 / 1080;
  const int colL = gx0w > 0 ? gx0w * 4 - 1 : 0;
  const int colR = gx63w < 1079 ? gx63w * 4 + 4 : IMG - 1;

  // halo gather: one masked vmem, 36 active lanes
  const int slot = lane & 31;
  const bool isR = lane >= 32;
  float hv = 0.f;
  if (slot < 18) {
    const int rr_h = slot / 3, ic_h = slot % 3;
    const int gyh = isR ? gy63w : gy0w;
    int rowh = gyh * 4 - 1 + rr_h;
    if (REDGE) rowh = rowh < 0 ? 0 : (rowh > IMG - 1 ? IMG - 1 : rowh);
    const int colh = isR ? colR : colL;
    hv = x[(size_t)ic_h * IMG * IMG + (size_t)rowh * IMG + colh];
  }

  // main loads: 18 float4
  float4 m[6][3];
  #pragma unroll
  for (int rr = 0; rr < 6; ++rr) {
    int row = r0 - 1 + rr;
    if (REDGE) row = row < 0 ? 0 : (row > IMG - 1 ? IMG - 1 : row);
    const size_t rbase = (size_t)row * IMG + c0;
    #pragma unroll
    for (int ic = 0; ic < 3; ++ic)
      m[rr][ic] = *(const float4*)(x + (size_t)ic * IMG * IMG + rbase);
  }

  // assemble 6-wide windows
  float s[6][3][6];
  #pragma unroll
  for (int rr = 0; rr < 6; ++rr) {
    const bool rok = REDGE ? ((unsigned)(r0 - 1 + rr) < (unsigned)IMG) : true;
    #pragma unroll
    for (int ic = 0; ic < 3; ++ic) {
      float vlv = __shfl_up(m[rr][ic].w, 1);
      float vrv = __shfl_down(m[rr][ic].x, 1);
      const float hL = __shfl(hv, rr * 3 + ic);
      const float hR = __shfl(hv, 32 + rr * 3 + ic);
      vlv = (lane == 0) ? hL : vlv;
      vrv = (lane == 63) ? hR : vrv;
      s[rr][ic][0] = (okL && rok) ? vlv : 0.f;
      s[rr][ic][1] = rok ? m[rr][ic].x : 0.f;
      s[rr][ic][2] = rok ? m[rr][ic].y : 0.f;
      s[rr][ic][3] = rok ? m[rr][ic].z : 0.f;
      s[rr][ic][4] = rok ? m[rr][ic].w : 0.f;
      s[rr][ic][5] = (okR && rok) ? vrv : 0.f;
    }
  }

  float acc[3][4][4];
  #pragma unroll
  for (int oc = 0; oc < 3; ++oc) {
    const float bb = b1[oc];
    #pragma unroll
    for (int r = 0; r < 4; ++r)
      #pragma unroll
      for (int j = 0; j < 4; ++j) acc[oc][r][j] = bb;
  }
  #pragma unroll
  for (int oc = 0; oc < 3; ++oc)
    #pragma unroll
    for (int ic = 0; ic < 3; ++ic)
      #pragma unroll
      for (int dy = 0; dy < 3; ++dy)
        #pragma unroll
        for (int dx = 0; dx < 3; ++dx) {
          const float w = w1[oc * 27 + ic * 9 + dy * 3 + dx];
          #pragma unroll
          for (int r = 0; r < 4; ++r)
            #pragma unroll
            for (int j = 0; j < 4; ++j)
              acc[oc][r][j] += s[r + dy][ic][j + dx] * w;
        }
  #pragma unroll
  for (int oc = 0; oc < 3; ++oc)
    #pragma unroll
    for (int r = 0; r < 4; ++r) {
      ushort4 h;
      h.x = f2bf(acc[oc][r][0]); h.y = f2bf(acc[oc][r][1]);
      h.z = f2bf(acc[oc][r][2]); h.w = f2bf(acc[oc][r][3]);
      *(ushort4*)(c1 + (size_t)oc * IMG * IMG + (size_t)(r0 + r) * IMG + c0) = h;
    }
}

__global__ __launch_bounds__(256, 2) void k_conv1(
    const float* __restrict__ x, const float* __restrict__ w1,
    const float* __restrict__ b1, u16* __restrict__ c1) {
  const int g = blockIdx.x * 256 + threadIdx.x;
  if (g >= 1080 * 1080) return;
  const int gx = g % 1080, gy = g / 1080;
  const int gy_min = (blockIdx.x * 256) / 1080;
  const int gy_max = (blockIdx.x * 256 + 255) / 1080;
  if (gy_min == 0 || gy_max >= 1079) conv1_body<true>(g, gx, gy, x, w1, b1, c1);
  else                               conv1_body<false>(g, gx, gy, x, w1, b1, c1);
}

// ============================================================================
// Stage 1b: conv2 + 2x2 maxpool (c1 bf16 -> h2 fp32), 2x2 pooled per thread,
// same shfl-halo scheme: 18 ushort4 + 1 gathered fixup (was 54 vmem).
// ============================================================================
template<bool REDGE>
__device__ __forceinline__ void conv2_body(
    const int g, const int gx, const int gy,
    const u16* __restrict__ c1, const float* __restrict__ w2,
    const float* __restrict__ b2, float* __restrict__ h2) {
  const int lane = threadIdx.x & 63;
  const int c0 = gx * 4, r0 = gy * 4;
  const bool okL = gx > 0, okR = gx < 1079;

  const int g0 = __builtin_amdgcn_readfirstlane(g - lane);
  const int g63 = g0 + 63;
  const int gx0w = g0 % 1080, gy0w = g0 / 1080;
  const int gx63w = g63 % 1080, gy63w = g63 / 1080;
  const int colL = gx0w > 0 ? gx0w * 4 - 1 : 0;
  const int colR = gx63w < 1079 ? gx63w * 4 + 4 : IMG - 1;

  const int slot = lane & 31;
  const bool isR = lane >= 32;
  float hv = 0.f;
  if (slot < 18) {
    const int rr_h = slot / 3, ic_h = slot % 3;
    const int gyh = isR ? gy63w : gy0w;
    int rowh = gyh * 4 - 1 + rr_h;
    if (REDGE) rowh = rowh < 0 ? 0 : (rowh > IMG - 1 ? IMG - 1 : rowh);
    const int colh = isR ? colR : colL;
    hv = bf2f(c1[(size_t)ic_h * IMG * IMG + (size_t)rowh * IMG + colh]);
  }

  ushort4 mv[6][3];
  #pragma unroll
  for (int rr = 0; rr < 6; ++rr) {
    int row = r0 - 1 + rr;
    if (REDGE) row = row < 0 ? 0 : (row > IMG - 1 ? IMG - 1 : row);
    const size_t rbase = (size_t)row * IMG + c0;
    #pragma unroll
    for (int ic = 0; ic < 3; ++ic)
      mv[rr][ic] = *(const ushort4*)(c1 + (size_t)ic * IMG * IMG + rbase);
  }

  float s[6][3][6];
  #pragma unroll
  for (int rr = 0; rr < 6; ++rr) {
    const bool rok = REDGE ? ((unsigned)(r0 - 1 + rr) < (unsigned)IMG) : true;
    #pragma unroll
    for (int ic = 0; ic < 3; ++ic) {
      const float f0 = bf2f(mv[rr][ic].x);
      const float f3 = bf2f(mv[rr][ic].w);
      float vlv = __shfl_up(f3, 1);
      float vrv = __shfl_down(f0, 1);
      const float hL = __shfl(hv, rr * 3 + ic);
      const float hR = __shfl(hv, 32 + rr * 3 + ic);
      vlv = (lane == 0) ? hL : vlv;
      vrv = (lane == 63) ? hR : vrv;
      s[rr][ic][0] = (okL && rok) ? vlv : 0.f;
      s[rr][ic][1] = rok ? f0 : 0.f;
      s[rr][ic][2] = rok ? bf2f(mv[rr][ic].y) : 0.f;
      s[rr][ic][3] = rok ? bf2f(mv[rr][ic].z) : 0.f;
      s[rr][ic][4] = rok ? f3 : 0.f;
      s[rr][ic][5] = (okR && rok) ? vrv : 0.f;
    }
  }

  float pm[2][2][2];
  #pragma unroll
  for (int oc = 0; oc < 2; ++oc)
    #pragma unroll
    for (int a = 0; a < 2; ++a)
      #pragma unroll
      for (int b = 0; b < 2; ++b) pm[oc][a][b] = -INFINITY;
  #pragma unroll
  for (int cr = 0; cr < 4; ++cr) {
    float v[2][4];
    #pragma unroll
    for (int oc = 0; oc < 2; ++oc) {
      const float bb = b2[oc];
      #pragma unroll
      for (int cc = 0; cc < 4; ++cc) v[oc][cc] = bb;
    }
    #pragma unroll
    for (int oc = 0; oc < 2; ++oc)
      #pragma unroll
      for (int ic = 0; ic < 3; ++ic)
        #pragma unroll
        for (int dy = 0; dy < 3; ++dy)
          #pragma unroll
          for (int dx = 0; dx < 3; ++dx) {
            const float w = w2[oc * 27 + ic * 9 + dy * 3 + dx];
            #pragma unroll
            for (int cc = 0; cc < 4; ++cc)
              v[oc][cc] += s[cr + dy][ic][cc + dx] * w;
          }
    #pragma unroll
    for (int oc = 0; oc < 2; ++oc)
      #pragma unroll
      for (int cc = 0; cc < 4; ++cc)
        pm[oc][cr >> 1][cc >> 1] = fmaxf(pm[oc][cr >> 1][cc >> 1], v[oc][cc]);
  }
  #pragma unroll
  for (int oc = 0; oc < 2; ++oc)
    #pragma unroll
    for (int rp = 0; rp < 2; ++rp) {
      float2 o;
      o.x = pm[oc][rp][0];
      o.y = pm[oc][rp][1];
      *(float2*)(h2 + (size_t)oc * H2D * H2D + (size_t)(gy * 2 + rp) * H2D + gx * 2) = o;
    }
}

__global__ __launch_bounds__(256, 2) void k_conv2pool(
    const u16* __restrict__ c1, const float* __restrict__ w2,
    const float* __restrict__ b2, float* __restrict__ h2) {
  const int g = blockIdx.x * 256 + threadIdx.x;
  if (g >= 1080 * 1080) return;
  const int gx = g % 1080, gy = g / 1080;
  const int gy_min = (blockIdx.x * 256) / 1080;
  const int gy_max = (blockIdx.x * 256 + 255) / 1080;
  if (gy_min == 0 || gy_max >= 1079) conv2_body<true>(g, gx, gy, c1, w2, b2, h2);
  else                               conv2_body<false>(g, gx, gy, c1, w2, b2, h2);
}

// ============================================================================
// Stage 2 (FUSED): conv3 -> conv4 -> maxpool2 (h2 -> red [1080,1080]) via LDS
// ============================================================================
__global__ __launch_bounds__(256) void k2_backbone2(
    const float* __restrict__ h2,
    const float* __restrict__ w3, const float* __restrict__ b3,
    const float* __restrict__ w4, const float* __restrict__ b4,
    float* __restrict__ red) {
  __shared__ float hs[2][34][36];
  __shared__ float c3s[2][32][36];
  const int tid = threadIdx.x;
  const int bx = blockIdx.x, by = blockIdx.y;
  const int gy0 = by * 30 - 2, gx0 = bx * 30 - 2;
  float W3[36], B3[2];
  #pragma unroll
  for (int i = 0; i < 36; ++i) W3[i] = w3[i];
  B3[0] = b3[0]; B3[1] = b3[1];
  for (int l = tid; l < 2 * 34 * 34; l += 256) {
    int c = l / 1156, rem = l % 1156, r = rem / 34, cc = rem % 34;
    int gy = gy0 + r, gx = gx0 + cc;
    float v = 0.f;
    if ((unsigned)gy < H2D && (unsigned)gx < H2D)
      v = h2[(size_t)c * H2D * H2D + (size_t)gy * H2D + gx];
    hs[c][r][cc] = v;
  }
  __syncthreads();
  {
    const int r = tid >> 3;
    const int c4 = (tid & 7) << 2;
    float acc[2][4];
    #pragma unroll
    for (int oc = 0; oc < 2; ++oc)
      #pragma unroll
      for (int j = 0; j < 4; ++j) acc[oc][j] = B3[oc];
    #pragma unroll
    for (int ic = 0; ic < 2; ++ic) {
      float xr[3][8];
      #pragma unroll
      for (int dy = 0; dy < 3; ++dy) {
        const float4 q0 = *(const float4*)&hs[ic][r + dy][c4];
        const float4 q1 = *(const float4*)&hs[ic][r + dy][c4 + 4];
        xr[dy][0] = q0.x; xr[dy][1] = q0.y; xr[dy][2] = q0.z; xr[dy][3] = q0.w;
        xr[dy][4] = q1.x; xr[dy][5] = q1.y; xr[dy][6] = q1.z; xr[dy][7] = q1.w;
      }
      #pragma unroll
      for (int oc = 0; oc < 2; ++oc)
        #pragma unroll
        for (int dy = 0; dy < 3; ++dy)
          #pragma unroll
          for (int dx = 0; dx < 3; ++dx) {
            const float w = W3[oc * 18 + ic * 9 + dy * 3 + dx];
            #pragma unroll
            for (int j = 0; j < 4; ++j) acc[oc][j] += xr[dy][j + dx] * w;
          }
    }
    const int gy = by * 30 - 1 + r;
    const bool rOK = (unsigned)gy < H2D;
    const int gxb = bx * 30 - 1 + c4;
    #pragma unroll
    for (int oc = 0; oc < 2; ++oc) {
      float4 o;
      o.x = (rOK && (unsigned)(gxb + 0) < H2D) ? acc[oc][0] : 0.f;
      o.y = (rOK && (unsigned)(gxb + 1) < H2D) ? acc[oc][1] : 0.f;
      o.z = (rOK && (unsigned)(gxb + 2) < H2D) ? acc[oc][2] : 0.f;
      o.w = (rOK && (unsigned)(gxb + 3) < H2D) ? acc[oc][3] : 0.f;
      *(float4*)&c3s[oc][r][c4] = o;
    }
  }
  __syncthreads();
  float W4[18], B4;
  #pragma unroll
  for (int i = 0; i < 18; ++i) W4[i] = w4[i];
  B4 = b4[0];
  const int ty = tid >> 4, tx = tid & 15;
  if (ty < 15 && tx < 15) {
    float cr[2][4][4];
    #pragma unroll
    for (int ic = 0; ic < 2; ++ic)
      #pragma unroll
      for (int rr = 0; rr < 4; ++rr) {
        const float2 p0 = *(const float2*)&c3s[ic][2 * ty + rr][2 * tx];
        const float2 p1 = *(const float2*)&c3s[ic][2 * ty + rr][2 * tx + 2];
        cr[ic][rr][0] = p0.x; cr[ic][rr][1] = p0.y;
        cr[ic][rr][2] = p1.x; cr[ic][rr][3] = p1.y;
      }
    float m = -INFINITY;
    #pragma unroll
    for (int sy = 0; sy < 2; ++sy)
      #pragma unroll
      for (int sx = 0; sx < 2; ++sx) {
        float a = B4;
        #pragma unroll
        for (int ic = 0; ic < 2; ++ic)
          #pragma unroll
          for (int dy = 0; dy < 3; ++dy)
            #pragma unroll
            for (int dx = 0; dx < 3; ++dx)
              a += cr[ic][sy + dy][sx + dx] * W4[ic * 9 + dy * 3 + dx];
        m = fmaxf(m, a);
      }
    red[(size_t)(by * 15 + ty) * FMD + (bx * 15 + tx)] = m;
  }
}

// ============ fallback stage-1 fused kernel (small-ws path) ============
__global__ __launch_bounds__(256) void k1_backbone1(
    const float* __restrict__ x,
    const float* __restrict__ w1, const float* __restrict__ b1,
    const float* __restrict__ w2, const float* __restrict__ b2,
    float* __restrict__ h2) {
  __shared__ float xs[3][34][36];
  __shared__ float c1s[3][32][36];
  const int tid = threadIdx.x;
  const int bx = blockIdx.x, by = blockIdx.y;
  const int gy0 = by * 30 - 2, gx0 = bx * 30 - 2;
  float W1[81], B1[3];
  #pragma unroll
  for (int i = 0; i < 81; ++i) W1[i] = w1[i];
  #pragma unroll
  for (int i = 0; i < 3; ++i) B1[i] = b1[i];
  for (int l = tid; l < 3 * 34 * 34; l += 256) {
    int c = l / 1156, rem = l % 1156, r = rem / 34, cc = rem % 34;
    int gy = gy0 + r, gx = gx0 + cc;
    float v = 0.f;
    if ((unsigned)gy < IMG && (unsigned)gx < IMG)
      v = x[(size_t)c * IMG * IMG + (size_t)gy * IMG + gx];
    xs[c][r][cc] = v;
  }
  __syncthreads();
  {
    const int r = tid >> 3;
    const int c4 = (tid & 7) << 2;
    float acc[3][4];
    #pragma unroll
    for (int oc = 0; oc < 3; ++oc)
      #pragma unroll
      for (int j = 0; j < 4; ++j) acc[oc][j] = B1[oc];
    #pragma unroll
    for (int ic = 0; ic < 3; ++ic) {
      float xr[3][8];
      #pragma unroll
      for (int dy = 0; dy < 3; ++dy) {
        const float4 q0 = *(const float4*)&xs[ic][r + dy][c4];
        const float4 q1 = *(const float4*)&xs[ic][r + dy][c4 + 4];
        xr[dy][0] = q0.x; xr[dy][1] = q0.y; xr[dy][2] = q0.z; xr[dy][3] = q0.w;
        xr[dy][4] = q1.x; xr[dy][5] = q1.y; xr[dy][6] = q1.z; xr[dy][7] = q1.w;
      }
      #pragma unroll
      for (int oc = 0; oc < 3; ++oc)
        #pragma unroll
        for (int dy = 0; dy < 3; ++dy)
          #pragma unroll
          for (int dx = 0; dx < 3; ++dx) {
            const float w = W1[oc * 27 + ic * 9 + dy * 3 + dx];
            #pragma unroll
            for (int j = 0; j < 4; ++j) acc[oc][j] += xr[dy][j + dx] * w;
          }
    }
    const int gy = by * 30 - 1 + r;
    const bool rOK = (unsigned)gy < IMG;
    const int gxb = bx * 30 - 1 + c4;
    #pragma unroll
    for (int oc = 0; oc < 3; ++oc) {
      float4 o;
      o.x = (rOK && (unsigned)(gxb + 0) < IMG) ? acc[oc][0] : 0.f;
      o.y = (rOK && (unsigned)(gxb + 1) < IMG) ? acc[oc][1] : 0.f;
      o.z = (rOK && (unsigned)(gxb + 2) < IMG) ? acc[oc][2] : 0.f;
      o.w = (rOK && (unsigned)(gxb + 3) < IMG) ? acc[oc][3] : 0.f;
      *(float4*)&c1s[oc][r][c4] = o;
    }
  }
  __syncthreads();
  float W2[54], B2[2];
  #pragma unroll
  for (int i = 0; i < 54; ++i) W2[i] = w2[i];
  B2[0] = b2[0]; B2[1] = b2[1];
  const int ty = tid >> 4, tx = tid & 15;
  if (ty < 15 && tx < 15) {
    float cr[3][4][4];
    #pragma unroll
    for (int ic = 0; ic < 3; ++ic)
      #pragma unroll
      for (int rr = 0; rr < 4; ++rr) {
        const float2 p0 = *(const float2*)&c1s[ic][2 * ty + rr][2 * tx];
        const float2 p1 = *(const float2*)&c1s[ic][2 * ty + rr][2 * tx + 2];
        cr[ic][rr][0] = p0.x; cr[ic][rr][1] = p0.y;
        cr[ic][rr][2] = p1.x; cr[ic][rr][3] = p1.y;
      }
    float m0 = -INFINITY, m1 = -INFINITY;
    #pragma unroll
    for (int sy = 0; sy < 2; ++sy)
      #pragma unroll
      for (int sx = 0; sx < 2; ++sx) {
        float a0 = B2[0], a1 = B2[1];
        #pragma unroll
        for (int ic = 0; ic < 3; ++ic)
          #pragma unroll
          for (int dy = 0; dy < 3; ++dy)
            #pragma unroll
            for (int dx = 0; dx < 3; ++dx) {
              const float v = cr[ic][sy + dy][sx + dx];
              a0 += v * W2[ic * 9 + dy * 3 + dx];
              a1 += v * W2[27 + ic * 9 + dy * 3 + dx];
            }
        m0 = fmaxf(m0, a0);
        m1 = fmaxf(m1, a1);
      }
    const size_t o = (size_t)(by * 15 + ty) * H2D + (bx * 15 + tx);
    h2[o] = m0;
    h2[(size_t)H2D * H2D + o] = m1;
  }
}

// ============ K3: rpn_conv (50x50, stride 50)  (reduced -> y [2,21,21]) ============
__global__ __launch_bounds__(256) void k3_rpnconv(
    const float* __restrict__ red,
    const float* __restrict__ w, const float* __restrict__ b,
    float* __restrict__ y) {
  __shared__ float part[256];
  const int cell = blockIdx.x;
  const int i = cell / FF, j = cell % FF;
  const int tid = threadIdx.x;
  float a0 = 0.f, a1 = 0.f;
  for (int t = tid; t < 2500; t += 256) {
    int ay = t / 50, ax = t % 50;
    float v = red[(size_t)(50 * i + ay) * FMD + 50 * j + ax];
    a0 += v * w[t];
    a1 += v * w[2500 + t];
  }
  part[tid] = a0;
  __syncthreads();
  for (int s = 128; s > 0; s >>= 1) {
    if (tid < s) part[tid] += part[tid + s];
    __syncthreads();
  }
  if (tid == 0) y[cell] = part[0] + b[0];
  __syncthreads();
  part[tid] = a1;
  __syncthreads();
  for (int s = 128; s > 0; s >>= 1) {
    if (tid < s) part[tid] += part[tid + s];
    __syncthreads();
  }
  if (tid == 0) y[441 + cell] = part[0] + b[1];
}

// ============ K4: rpn heads + faithful masked-select + proposals/rects ============
__global__ __launch_bounds__(512) void k4_select(
    const float* __restrict__ y,
    const float* __restrict__ bbw, const float* __restrict__ bbb,
    const float* __restrict__ clw, const float* __restrict__ clb,
    float* __restrict__ props_out, int* __restrict__ rects,
    unsigned* __restrict__ pooled_m) {
  __shared__ float ys[2][23][23];
  __shared__ unsigned char flag[6][441];
  __shared__ short pos[6][20];
  __shared__ int cnt[6];
  __shared__ int selT[20];
  __shared__ float offv[20], anchv[20];
  const int tid = threadIdx.x;
  for (int l = tid; l < 2 * 23 * 23; l += 512) ((float*)ys)[l] = 0.f;
  __syncthreads();
  for (int l = tid; l < 2 * 441; l += 512) {
    int c = l / 441, p = l % 441;
    ys[c][p / 21 + 1][p % 21 + 1] = y[l];
  }
  __syncthreads();
  for (int l = tid; l < 6 * 441; l += 512) {
    int a = l / 441, p = l % 441, i = p / 21, j = p % 21;
    float v = clb[a];
    #pragma unroll
    for (int c2 = 0; c2 < 2; c2++)
      #pragma unroll
      for (int dy = 0; dy < 3; dy++)
        #pragma unroll
        for (int dx = 0; dx < 3; dx++)
          v += ys[c2][i + dy][j + dx] * clw[a * 18 + c2 * 9 + dy * 3 + dx];
    flag[a][p] = (tanhf(v) > 0.95f) ? 1 : 0;
  }
  __syncthreads();
  if (tid < 6) {
    int c = 0;
    for (int p = 0; p < 441; p++)
      if (flag[tid][p]) {
        if (c < 20) pos[tid][c] = (short)p;
        c++;
      }
    cnt[tid] = c;
  }
  __syncthreads();
  if (tid == 0) {
    int s = 0;
    for (int g = 0; g < 24 && s < 20; g++) {
      int a = g >> 2;
      int take = cnt[a] < 20 - s ? cnt[a] : 20 - s;
      for (int r = 0; r < take; r++) selT[s++] = g * 441 + (int)pos[a][r];
    }
    if (s < 20) {
      for (int t = 0; t < 10584 && s < 20; t++) {
        int a = t / 1764, p = t % 441;
        if (!flag[a][p]) selT[s++] = t;
      }
    }
  }
  __syncthreads();
  if (tid < 20) {
    int t = selT[tid];
    int ch = t / 441, p = t % 441, i = p / 21, j = p % 21;
    int a = ch >> 2, c = ch & 3;
    float v = bbb[ch];
    #pragma unroll
    for (int c2 = 0; c2 < 2; c2++)
      #pragma unroll
      for (int dy = 0; dy < 3; dy++)
        #pragma unroll
        for (int dx = 0; dx < 3; dx++)
          v += ys[c2][i + dy][j + dx] * bbw[ch * 18 + c2 * 9 + dy * 3 + dx];
    offv[tid] = v;
    float sz = (a < 3) ? 1.f : 2.f;
    int am = a % 3;
    float ar = (am == 0) ? 0.5f : (am == 1 ? 1.f : 2.f);
    float base;
    if (c == 0) base = 0.f;
    else if (c == 1) base = sz * -(ar - 1.f) * 0.5f;
    else if (c == 2) base = sz;
    else base = sz * (1.f + (ar - 1.f) * 0.5f);
    anchv[tid] = base + ((c & 1) ? (float)j : (float)i);
  }
  __syncthreads();
  if (tid < 5) {
    int k = tid;
    float o0 = offv[4 * k], o1 = offv[4 * k + 1], o2 = offv[4 * k + 2], o3 = offv[4 * k + 3];
    float a0 = anchv[4 * k], a2 = anchv[4 * k + 2], a3 = anchv[4 * k + 3];
    float p0 = fminf(fmaxf(o0 + a0 - a2 * 0.5f, 0.f), 21.f) * 50.f;
    float p1 = fminf(fmaxf(o1 - a3 * 0.5f, 0.f), 21.f) * 50.f;
    float p2 = fminf(fmaxf(o2 + a0 + a2 * 0.5f, 0.f), 21.f) * 50.f;
    float p3 = fminf(fmaxf(o3 + a3 * 0.5f, 0.f), 21.f) * 50.f;
    props_out[k * 4 + 0] = p0;
    props_out[k * 4 + 1] = p1;
    props_out[k * 4 + 2] = p2;
    props_out[k * 4 + 3] = p3;
    float x1 = rintf(p0), y1 = rintf(p1), x2 = rintf(p2), y2 = rintf(p3);
    float bwf = fmaxf(x2 - x1 + 1.f, 1.f) * 0.5f;
    float bhf = fmaxf(y2 - y1 + 1.f, 1.f) * 0.5f;
    for (int ph = 0; ph < 2; ph++)
      for (int pw = 0; pw < 2; pw++) {
        int hsv = (int)fminf(fmaxf(floorf((float)ph * bhf) + y1, 0.f), 1080.f);
        int hev = (int)fminf(fmaxf(ceilf((float)(ph + 1) * bhf) + y1, 0.f), 1080.f);
        int wsv = (int)fminf(fmaxf(floorf((float)pw * bwf) + x1, 0.f), 1080.f);
        int wev = (int)fminf(fmaxf(ceilf((float)(pw + 1) * bwf) + x1, 0.f), 1080.f);
        int idx = k * 4 + ph * 2 + pw;
        rects[idx * 4 + 0] = hsv;
        rects[idx * 4 + 1] = hev;
        rects[idx * 4 + 2] = wsv;
        rects[idx * 4 + 3] = wev;
      }
  }
  if (tid >= 32 && tid < 52) pooled_m[tid - 32] = 0x007FFFFFu;  // mapped(-inf)
}

// ============ K5: RoI max pool (atomicMax on order-preserving uint map) ============
__global__ __launch_bounds__(256) void k5_roipool(
    const float* __restrict__ red, const int* __restrict__ rects,
    unsigned* __restrict__ pooled_m) {
  const int cell = blockIdx.x;
  const int hs = rects[cell * 4 + 0], he = rects[cell * 4 + 1];
  const int wss = rects[cell * 4 + 2], wee = rects[cell * 4 + 3];
  const int nr = he - hs;
  if (nr <= 0 || wee <= wss) return;
  const int slice = blockIdx.y, nslice = gridDim.y;
  const int r0 = hs + (int)((long)nr * slice / nslice);
  const int r1 = hs + (int)((long)nr * (slice + 1) / nslice);
  float m = -INFINITY;
  for (int r = r0; r < r1; r++)
    for (int c = wss + (int)threadIdx.x; c < wee; c += 256)
      m = fmaxf(m, red[(size_t)r * FMD + c]);
  __shared__ float part[256];
  part[threadIdx.x] = m;
  __syncthreads();
  for (int s = 128; s > 0; s >>= 1) {
    if ((int)threadIdx.x < s) part[threadIdx.x] = fmaxf(part[threadIdx.x], part[threadIdx.x + s]);
    __syncthreads();
  }
  if (threadIdx.x == 0 && part[0] > -INFINITY) {
    unsigned u = __float_as_uint(part[0]);
    u = (u & 0x80000000u) ? ~u : (u | 0x80000000u);
    atomicMax(&pooled_m[cell], u);
  }
}

// ============ K6: fc / box / cls heads -> d_out (30 floats) ============
__global__ void k6_heads(
    const unsigned* __restrict__ pooled_m, const float* __restrict__ props,
    const float* __restrict__ fcw, const float* __restrict__ fcb,
    const float* __restrict__ bxw, const float* __restrict__ bxb,
    const float* __restrict__ clw, const float* __restrict__ clb,
    float* __restrict__ out) {
  if (threadIdx.x != 0 || blockIdx.x != 0) return;
  float pooled[5][4];
  for (int i = 0; i < 20; i++) {
    unsigned u = pooled_m[i];
    float f = (u & 0x80000000u) ? __uint_as_float(u ^ 0x80000000u) : __uint_as_float(~u);
    if (!isfinite(f)) f = 0.f;
    pooled[i / 4][i % 4] = f;
  }
  for (int k = 0; k < 5; k++) {
    float fc[12];
    for (int m = 0; m < 12; m++) {
      float v = fcb[m];
      for (int n = 0; n < 4; n++) v += pooled[k][n] * fcw[m * 4 + n];
      fc[m] = v;
    }
    float bo[4];
    for (int c = 0; c < 4; c++) {
      float v = bxb[c];
      for (int m = 0; m < 12; m++) v += fc[m] * bxw[c * 12 + m];
      bo[c] = v;
    }
    float p0 = props[k * 4], p1 = props[k * 4 + 1], p2 = props[k * 4 + 2], p3 = props[k * 4 + 3];
    out[k * 4 + 0] = fminf(fmaxf(p0 + bo[0] - bo[2] * 0.5f, 0.f), 3.f);
    out[k * 4 + 1] = fminf(fmaxf(p1 - bo[3] * 0.5f, 0.f), 1.f);
    out[k * 4 + 2] = fminf(fmaxf(p2 + bo[0] + bo[2] * 0.5f, 0.f), 3.f);
    out[k * 4 + 3] = fminf(fmaxf(p3 + bo[3] * 0.5f, 0.f), 1.f);
    float l0 = clb[0], l1 = clb[1];
    for (int m = 0; m < 12; m++) {
      l0 += fc[m] * clw[m];
      l1 += fc[m] * clw[12 + m];
    }
    float mx = fmaxf(l0, l1);
    float e0 = expf(l0 - mx), e1 = expf(l1 - mx);
    out[20 + k * 2 + 0] = e0 / (e0 + e1);
    out[20 + k * 2 + 1] = e1 / (e0 + e1);
  }
}

extern "C" void kernel_launch(void* const* d_in, const int* in_sizes, int n_in,
                              void* d_out, int out_size, void* d_ws, size_t ws_size,
                              hipStream_t stream) {
  const float* x   = (const float*)d_in[0];
  const float* w1  = (const float*)d_in[1];
  const float* b1  = (const float*)d_in[2];
  const float* w2  = (const float*)d_in[3];
  const float* b2  = (const float*)d_in[4];
  const float* w3  = (const float*)d_in[5];
  const float* b3  = (const float*)d_in[6];
  const float* w4  = (const float*)d_in[7];
  const float* b4  = (const float*)d_in[8];
  const float* rw  = (const float*)d_in[9];
  const float* rb  = (const float*)d_in[10];
  const float* bbw = (const float*)d_in[11];
  const float* bbb = (const float*)d_in[12];
  const float* clw = (const float*)d_in[13];
  const float* clb = (const float*)d_in[14];
  const float* fcw = (const float*)d_in[15];
  const float* fcb = (const float*)d_in[16];
  const float* bxw = (const float*)d_in[17];
  const float* bxb = (const float*)d_in[18];
  const float* c2w = (const float*)d_in[19];
  const float* c2b = (const float*)d_in[20];

  char* wsb = (char*)d_ws;

  if (ws_size >= 160000000ull) {
    // split path: c1(bf16) | h2 | red | small
    u16*   c1u = (u16*)wsb;
    float* h2  = (float*)(wsb + 111974400);
    float* red = (float*)(wsb + 149299200);
    float* yv  = (float*)(wsb + 153964800);
    float* props = yv + 882;
    int*   rects = (int*)(props + 20);
    unsigned* pooled_m = (unsigned*)(rects + 80);

    k_conv1    <<<4557, 256, 0, stream>>>(x, w1, b1, c1u);
    k_conv2pool<<<4557, 256, 0, stream>>>(c1u, w2, b2, h2);
    k2_backbone2<<<dim3(72, 72), 256, 0, stream>>>(h2, w3, b3, w4, b4, red);
    k3_rpnconv<<<441, 256, 0, stream>>>(red, rw, rb, yv);
    k4_select<<<1, 512, 0, stream>>>(yv, bbw, bbb, clw, clb, props, rects, pooled_m);
    k5_roipool<<<dim3(20, 16), 256, 0, stream>>>(red, rects, pooled_m);
    k6_heads<<<1, 64, 0, stream>>>(pooled_m, props, fcw, fcb, bxw, bxb, c2w, c2b,
                                   (float*)d_out);
  } else {
    // fallback: round-2 fused path (42 MB workspace)
    float* ws = (float*)d_ws;
    float* h2 = ws;
    float* red = ws + 9331200;
    float* yv = ws + 10497600;
    float* props = ws + 10498482;
    int* rects = (int*)(ws + 10498502);
    unsigned* pooled_m = (unsigned*)(ws + 10498582);

    k1_backbone1<<<dim3(144, 144), 256, 0, stream>>>(x, w1, b1, w2, b2, h2);
    k2_backbone2<<<dim3(72, 72), 256, 0, stream>>>(h2, w3, b3, w4, b4, red);
    k3_rpnconv<<<441, 256, 0, stream>>>(red, rw, rb, yv);
    k4_select<<<1, 512, 0, stream>>>(yv, bbw, bbb, clw, clb, props, rects, pooled_m);
    k5_roipool<<<dim3(20, 16), 256, 0, stream>>>(red, rects, pooled_m);
    k6_heads<<<1, 64, 0, stream>>>(pooled_m, props, fcw, fcb, bxw, bxb, c2w, c2b,
                                   (float*)d_out);
  }
}

// Round 13
// 205.441 us; speedup vs baseline: 1.6177x; 1.0244x over previous
//
#include <hip/hip_runtime.h>
#include <math.h>

#define IMG 4320
#define H2D 2160
#define FMD 1080
#define FF 21

typedef unsigned short u16;

__device__ __forceinline__ float bf2f(u16 h) {
  return __uint_as_float(((unsigned)h) << 16);
}
__device__ __forceinline__ u16 f2bf(float f) {  // RTNE
  unsigned u = __float_as_uint(f);
  unsigned r = 0x7FFFu + ((u >> 16) & 1u);
  return (u16)((u + r) >> 16);
}

// ============================================================================
// Stage 1a: conv1 (x fp32 -> c1 bf16), 4 rows x 4 cols per thread.
// Shfl-halo + per-input-row consume: stage 18 float4, then per row assemble
// an 18-float window and immediately accumulate into acc (no persistent
// s[6][3][6]) -> ~90 fewer live VGPRs -> higher natural occupancy.
// ============================================================================
template<bool REDGE>
__device__ __forceinline__ void conv1_body(
    const int g, const int gx, const int gy,
    const float* __restrict__ x, const float* __restrict__ w1,
    const float* __restrict__ b1, u16* __restrict__ c1) {
  const int lane = threadIdx.x & 63;
  const int c0 = gx * 4, r0 = gy * 4;
  const bool okL = gx > 0, okR = gx < 1079;

  // wave-uniform geometry of lane0 / lane63 for halo gather
  const int g0 = __builtin_amdgcn_readfirstlane(g - lane);
  const int g63 = g0 + 63;
  const int gx0w = g0 % 1080, gy0w = g0 / 1080;
  const int gx63w = g63 % 1080, gy63w = g63 / 1080;
  const int colL = gx0w > 0 ? gx0w * 4 - 1 : 0;
  const int colR = gx63w < 1079 ? gx63w * 4 + 4 : IMG - 1;

  // halo gather: one masked vmem, 36 active lanes
  const int slot = lane & 31;
  const bool isR = lane >= 32;
  float hv = 0.f;
  if (slot < 18) {
    const int rr_h = slot / 3, ic_h = slot % 3;
    const int gyh = isR ? gy63w : gy0w;
    int rowh = gyh * 4 - 1 + rr_h;
    if (REDGE) rowh = rowh < 0 ? 0 : (rowh > IMG - 1 ? IMG - 1 : rowh);
    const int colh = isR ? colR : colL;
    hv = x[(size_t)ic_h * IMG * IMG + (size_t)rowh * IMG + colh];
  }

  // main loads: 18 float4 (all issued before use)
  float4 m[6][3];
  #pragma unroll
  for (int rr = 0; rr < 6; ++rr) {
    int row = r0 - 1 + rr;
    if (REDGE) row = row < 0 ? 0 : (row > IMG - 1 ? IMG - 1 : row);
    const size_t rbase = (size_t)row * IMG + c0;
    #pragma unroll
    for (int ic = 0; ic < 3; ++ic)
      m[rr][ic] = *(const float4*)(x + (size_t)ic * IMG * IMG + rbase);
  }

  float acc[3][4][4];
  #pragma unroll
  for (int oc = 0; oc < 3; ++oc) {
    const float bb = b1[oc];
    #pragma unroll
    for (int r = 0; r < 4; ++r)
      #pragma unroll
      for (int j = 0; j < 4; ++j) acc[oc][r][j] = bb;
  }

  // per-input-row window assembly + immediate consume
  #pragma unroll
  for (int rr = 0; rr < 6; ++rr) {
    const bool rok = REDGE ? ((unsigned)(r0 - 1 + rr) < (unsigned)IMG) : true;
    float w6[3][6];
    #pragma unroll
    for (int ic = 0; ic < 3; ++ic) {
      float vlv = __shfl_up(m[rr][ic].w, 1);
      float vrv = __shfl_down(m[rr][ic].x, 1);
      const float hL = __shfl(hv, rr * 3 + ic);
      const float hR = __shfl(hv, 32 + rr * 3 + ic);
      vlv = (lane == 0) ? hL : vlv;
      vrv = (lane == 63) ? hR : vrv;
      w6[ic][0] = (okL && rok) ? vlv : 0.f;
      w6[ic][1] = rok ? m[rr][ic].x : 0.f;
      w6[ic][2] = rok ? m[rr][ic].y : 0.f;
      w6[ic][3] = rok ? m[rr][ic].z : 0.f;
      w6[ic][4] = rok ? m[rr][ic].w : 0.f;
      w6[ic][5] = (okR && rok) ? vrv : 0.f;
    }
    #pragma unroll
    for (int dy = 0; dy < 3; ++dy) {
      const int r = rr - dy;
      if (r >= 0 && r < 4) {
        #pragma unroll
        for (int oc = 0; oc < 3; ++oc)
          #pragma unroll
          for (int ic = 0; ic < 3; ++ic)
            #pragma unroll
            for (int dx = 0; dx < 3; ++dx) {
              const float w = w1[oc * 27 + ic * 9 + dy * 3 + dx];
              #pragma unroll
              for (int j = 0; j < 4; ++j)
                acc[oc][r][j] += w6[ic][j + dx] * w;
            }
      }
    }
  }

  #pragma unroll
  for (int oc = 0; oc < 3; ++oc)
    #pragma unroll
    for (int r = 0; r < 4; ++r) {
      ushort4 h;
      h.x = f2bf(acc[oc][r][0]); h.y = f2bf(acc[oc][r][1]);
      h.z = f2bf(acc[oc][r][2]); h.w = f2bf(acc[oc][r][3]);
      *(ushort4*)(c1 + (size_t)oc * IMG * IMG + (size_t)(r0 + r) * IMG + c0) = h;
    }
}

__global__ __launch_bounds__(256, 2) void k_conv1(
    const float* __restrict__ x, const float* __restrict__ w1,
    const float* __restrict__ b1, u16* __restrict__ c1) {
  const int g = blockIdx.x * 256 + threadIdx.x;
  if (g >= 1080 * 1080) return;
  const int gx = g % 1080, gy = g / 1080;
  const int gy_min = (blockIdx.x * 256) / 1080;
  const int gy_max = (blockIdx.x * 256 + 255) / 1080;
  if (gy_min == 0 || gy_max >= 1079) conv1_body<true>(g, gx, gy, x, w1, b1, c1);
  else                               conv1_body<false>(g, gx, gy, x, w1, b1, c1);
}

// ============================================================================
// Stage 1b: conv2 + 2x2 maxpool (c1 bf16 -> h2 fp32), 2x2 pooled per thread,
// shfl-halo + per-input-row consume (v[2][4][4] conv accumulators, pool last).
// ============================================================================
template<bool REDGE>
__device__ __forceinline__ void conv2_body(
    const int g, const int gx, const int gy,
    const u16* __restrict__ c1, const float* __restrict__ w2,
    const float* __restrict__ b2, float* __restrict__ h2) {
  const int lane = threadIdx.x & 63;
  const int c0 = gx * 4, r0 = gy * 4;
  const bool okL = gx > 0, okR = gx < 1079;

  const int g0 = __builtin_amdgcn_readfirstlane(g - lane);
  const int g63 = g0 + 63;
  const int gx0w = g0 % 1080, gy0w = g0 / 1080;
  const int gx63w = g63 % 1080, gy63w = g63 / 1080;
  const int colL = gx0w > 0 ? gx0w * 4 - 1 : 0;
  const int colR = gx63w < 1079 ? gx63w * 4 + 4 : IMG - 1;

  const int slot = lane & 31;
  const bool isR = lane >= 32;
  float hv = 0.f;
  if (slot < 18) {
    const int rr_h = slot / 3, ic_h = slot % 3;
    const int gyh = isR ? gy63w : gy0w;
    int rowh = gyh * 4 - 1 + rr_h;
    if (REDGE) rowh = rowh < 0 ? 0 : (rowh > IMG - 1 ? IMG - 1 : rowh);
    const int colh = isR ? colR : colL;
    hv = bf2f(c1[(size_t)ic_h * IMG * IMG + (size_t)rowh * IMG + colh]);
  }

  ushort4 mv[6][3];
  #pragma unroll
  for (int rr = 0; rr < 6; ++rr) {
    int row = r0 - 1 + rr;
    if (REDGE) row = row < 0 ? 0 : (row > IMG - 1 ? IMG - 1 : row);
    const size_t rbase = (size_t)row * IMG + c0;
    #pragma unroll
    for (int ic = 0; ic < 3; ++ic)
      mv[rr][ic] = *(const ushort4*)(c1 + (size_t)ic * IMG * IMG + rbase);
  }

  float v[2][4][4];
  #pragma unroll
  for (int oc = 0; oc < 2; ++oc) {
    const float bb = b2[oc];
    #pragma unroll
    for (int cr = 0; cr < 4; ++cr)
      #pragma unroll
      for (int cc = 0; cc < 4; ++cc) v[oc][cr][cc] = bb;
  }

  #pragma unroll
  for (int rr = 0; rr < 6; ++rr) {
    const bool rok = REDGE ? ((unsigned)(r0 - 1 + rr) < (unsigned)IMG) : true;
    float w6[3][6];
    #pragma unroll
    for (int ic = 0; ic < 3; ++ic) {
      const float f0 = bf2f(mv[rr][ic].x);
      const float f3 = bf2f(mv[rr][ic].w);
      float vlv = __shfl_up(f3, 1);
      float vrv = __shfl_down(f0, 1);
      const float hL = __shfl(hv, rr * 3 + ic);
      const float hR = __shfl(hv, 32 + rr * 3 + ic);
      vlv = (lane == 0) ? hL : vlv;
      vrv = (lane == 63) ? hR : vrv;
      w6[ic][0] = (okL && rok) ? vlv : 0.f;
      w6[ic][1] = rok ? f0 : 0.f;
      w6[ic][2] = rok ? bf2f(mv[rr][ic].y) : 0.f;
      w6[ic][3] = rok ? bf2f(mv[rr][ic].z) : 0.f;
      w6[ic][4] = rok ? f3 : 0.f;
      w6[ic][5] = (okR && rok) ? vrv : 0.f;
    }
    #pragma unroll
    for (int dy = 0; dy < 3; ++dy) {
      const int cr = rr - dy;
      if (cr >= 0 && cr < 4) {
        #pragma unroll
        for (int oc = 0; oc < 2; ++oc)
          #pragma unroll
          for (int ic = 0; ic < 3; ++ic)
            #pragma unroll
            for (int dx = 0; dx < 3; ++dx) {
              const float w = w2[oc * 27 + ic * 9 + dy * 3 + dx];
              #pragma unroll
              for (int cc = 0; cc < 4; ++cc)
                v[oc][cr][cc] += w6[ic][cc + dx] * w;
            }
      }
    }
  }

  #pragma unroll
  for (int oc = 0; oc < 2; ++oc)
    #pragma unroll
    for (int rp = 0; rp < 2; ++rp) {
      float2 o;
      o.x = fmaxf(fmaxf(v[oc][2 * rp][0], v[oc][2 * rp][1]),
                  fmaxf(v[oc][2 * rp + 1][0], v[oc][2 * rp + 1][1]));
      o.y = fmaxf(fmaxf(v[oc][2 * rp][2], v[oc][2 * rp][3]),
                  fmaxf(v[oc][2 * rp + 1][2], v[oc][2 * rp + 1][3]));
      *(float2*)(h2 + (size_t)oc * H2D * H2D + (size_t)(gy * 2 + rp) * H2D + gx * 2) = o;
    }
}

__global__ __launch_bounds__(256, 2) void k_conv2pool(
    const u16* __restrict__ c1, const float* __restrict__ w2,
    const float* __restrict__ b2, float* __restrict__ h2) {
  const int g = blockIdx.x * 256 + threadIdx.x;
  if (g >= 1080 * 1080) return;
  const int gx = g % 1080, gy = g / 1080;
  const int gy_min = (blockIdx.x * 256) / 1080;
  const int gy_max = (blockIdx.x * 256 + 255) / 1080;
  if (gy_min == 0 || gy_max >= 1079) conv2_body<true>(g, gx, gy, c1, w2, b2, h2);
  else                               conv2_body<false>(g, gx, gy, c1, w2, b2, h2);
}

// ============================================================================
// Stage 2 (FUSED): conv3 -> conv4 -> maxpool2 (h2 -> red [1080,1080]) via LDS
// ============================================================================
__global__ __launch_bounds__(256) void k2_backbone2(
    const float* __restrict__ h2,
    const float* __restrict__ w3, const float* __restrict__ b3,
    const float* __restrict__ w4, const float* __restrict__ b4,
    float* __restrict__ red) {
  __shared__ float hs[2][34][36];
  __shared__ float c3s[2][32][36];
  const int tid = threadIdx.x;
  const int bx = blockIdx.x, by = blockIdx.y;
  const int gy0 = by * 30 - 2, gx0 = bx * 30 - 2;
  float W3[36], B3[2];
  #pragma unroll
  for (int i = 0; i < 36; ++i) W3[i] = w3[i];
  B3[0] = b3[0]; B3[1] = b3[1];
  for (int l = tid; l < 2 * 34 * 34; l += 256) {
    int c = l / 1156, rem = l % 1156, r = rem / 34, cc = rem % 34;
    int gy = gy0 + r, gx = gx0 + cc;
    float v = 0.f;
    if ((unsigned)gy < H2D && (unsigned)gx < H2D)
      v = h2[(size_t)c * H2D * H2D + (size_t)gy * H2D + gx];
    hs[c][r][cc] = v;
  }
  __syncthreads();
  {
    const int r = tid >> 3;
    const int c4 = (tid & 7) << 2;
    float acc[2][4];
    #pragma unroll
    for (int oc = 0; oc < 2; ++oc)
      #pragma unroll
      for (int j = 0; j < 4; ++j) acc[oc][j] = B3[oc];
    #pragma unroll
    for (int ic = 0; ic < 2; ++ic) {
      float xr[3][8];
      #pragma unroll
      for (int dy = 0; dy < 3; ++dy) {
        const float4 q0 = *(const float4*)&hs[ic][r + dy][c4];
        const float4 q1 = *(const float4*)&hs[ic][r + dy][c4 + 4];
        xr[dy][0] = q0.x; xr[dy][1] = q0.y; xr[dy][2] = q0.z; xr[dy][3] = q0.w;
        xr[dy][4] = q1.x; xr[dy][5] = q1.y; xr[dy][6] = q1.z; xr[dy][7] = q1.w;
      }
      #pragma unroll
      for (int oc = 0; oc < 2; ++oc)
        #pragma unroll
        for (int dy = 0; dy < 3; ++dy)
          #pragma unroll
          for (int dx = 0; dx < 3; ++dx) {
            const float w = W3[oc * 18 + ic * 9 + dy * 3 + dx];
            #pragma unroll
            for (int j = 0; j < 4; ++j) acc[oc][j] += xr[dy][j + dx] * w;
          }
    }
    const int gy = by * 30 - 1 + r;
    const bool rOK = (unsigned)gy < H2D;
    const int gxb = bx * 30 - 1 + c4;
    #pragma unroll
    for (int oc = 0; oc < 2; ++oc) {
      float4 o;
      o.x = (rOK && (unsigned)(gxb + 0) < H2D) ? acc[oc][0] : 0.f;
      o.y = (rOK && (unsigned)(gxb + 1) < H2D) ? acc[oc][1] : 0.f;
      o.z = (rOK && (unsigned)(gxb + 2) < H2D) ? acc[oc][2] : 0.f;
      o.w = (rOK && (unsigned)(gxb + 3) < H2D) ? acc[oc][3] : 0.f;
      *(float4*)&c3s[oc][r][c4] = o;
    }
  }
  __syncthreads();
  float W4[18], B4;
  #pragma unroll
  for (int i = 0; i < 18; ++i) W4[i] = w4[i];
  B4 = b4[0];
  const int ty = tid >> 4, tx = tid & 15;
  if (ty < 15 && tx < 15) {
    float cr[2][4][4];
    #pragma unroll
    for (int ic = 0; ic < 2; ++ic)
      #pragma unroll
      for (int rr = 0; rr < 4; ++rr) {
        const float2 p0 = *(const float2*)&c3s[ic][2 * ty + rr][2 * tx];
        const float2 p1 = *(const float2*)&c3s[ic][2 * ty + rr][2 * tx + 2];
        cr[ic][rr][0] = p0.x; cr[ic][rr][1] = p0.y;
        cr[ic][rr][2] = p1.x; cr[ic][rr][3] = p1.y;
      }
    float m = -INFINITY;
    #pragma unroll
    for (int sy = 0; sy < 2; ++sy)
      #pragma unroll
      for (int sx = 0; sx < 2; ++sx) {
        float a = B4;
        #pragma unroll
        for (int ic = 0; ic < 2; ++ic)
          #pragma unroll
          for (int dy = 0; dy < 3; ++dy)
            #pragma unroll
            for (int dx = 0; dx < 3; ++dx)
              a += cr[ic][sy + dy][sx + dx] * W4[ic * 9 + dy * 3 + dx];
        m = fmaxf(m, a);
      }
    red[(size_t)(by * 15 + ty) * FMD + (bx * 15 + tx)] = m;
  }
}

// ============ fallback stage-1 fused kernel (small-ws path) ============
__global__ __launch_bounds__(256) void k1_backbone1(
    const float* __restrict__ x,
    const float* __restrict__ w1, const float* __restrict__ b1,
    const float* __restrict__ w2, const float* __restrict__ b2,
    float* __restrict__ h2) {
  __shared__ float xs[3][34][36];
  __shared__ float c1s[3][32][36];
  const int tid = threadIdx.x;
  const int bx = blockIdx.x, by = blockIdx.y;
  const int gy0 = by * 30 - 2, gx0 = bx * 30 - 2;
  float W1[81], B1[3];
  #pragma unroll
  for (int i = 0; i < 81; ++i) W1[i] = w1[i];
  #pragma unroll
  for (int i = 0; i < 3; ++i) B1[i] = b1[i];
  for (int l = tid; l < 3 * 34 * 34; l += 256) {
    int c = l / 1156, rem = l % 1156, r = rem / 34, cc = rem % 34;
    int gy = gy0 + r, gx = gx0 + cc;
    float v = 0.f;
    if ((unsigned)gy < IMG && (unsigned)gx < IMG)
      v = x[(size_t)c * IMG * IMG + (size_t)gy * IMG + gx];
    xs[c][r][cc] = v;
  }
  __syncthreads();
  {
    const int r = tid >> 3;
    const int c4 = (tid & 7) << 2;
    float acc[3][4];
    #pragma unroll
    for (int oc = 0; oc < 3; ++oc)
      #pragma unroll
      for (int j = 0; j < 4; ++j) acc[oc][j] = B1[oc];
    #pragma unroll
    for (int ic = 0; ic < 3; ++ic) {
      float xr[3][8];
      #pragma unroll
      for (int dy = 0; dy < 3; ++dy) {
        const float4 q0 = *(const float4*)&xs[ic][r + dy][c4];
        const float4 q1 = *(const float4*)&xs[ic][r + dy][c4 + 4];
        xr[dy][0] = q0.x; xr[dy][1] = q0.y; xr[dy][2] = q0.z; xr[dy][3] = q0.w;
        xr[dy][4] = q1.x; xr[dy][5] = q1.y; xr[dy][6] = q1.z; xr[dy][7] = q1.w;
      }
      #pragma unroll
      for (int oc = 0; oc < 3; ++oc)
        #pragma unroll
        for (int dy = 0; dy < 3; ++dy)
          #pragma unroll
          for (int dx = 0; dx < 3; ++dx) {
            const float w = W1[oc * 27 + ic * 9 + dy * 3 + dx];
            #pragma unroll
            for (int j = 0; j < 4; ++j) acc[oc][j] += xr[dy][j + dx] * w;
          }
    }
    const int gy = by * 30 - 1 + r;
    const bool rOK = (unsigned)gy < IMG;
    const int gxb = bx * 30 - 1 + c4;
    #pragma unroll
    for (int oc = 0; oc < 3; ++oc) {
      float4 o;
      o.x = (rOK && (unsigned)(gxb + 0) < IMG) ? acc[oc][0] : 0.f;
      o.y = (rOK && (unsigned)(gxb + 1) < IMG) ? acc[oc][1] : 0.f;
      o.z = (rOK && (unsigned)(gxb + 2) < IMG) ? acc[oc][2] : 0.f;
      o.w = (rOK && (unsigned)(gxb + 3) < IMG) ? acc[oc][3] : 0.f;
      *(float4*)&c1s[oc][r][c4] = o;
    }
  }
  __syncthreads();
  float W2[54], B2[2];
  #pragma unroll
  for (int i = 0; i < 54; ++i) W2[i] = w2[i];
  B2[0] = b2[0]; B2[1] = b2[1];
  const int ty = tid >> 4, tx = tid & 15;
  if (ty < 15 && tx < 15) {
    float cr[3][4][4];
    #pragma unroll
    for (int ic = 0; ic < 3; ++ic)
      #pragma unroll
      for (int rr = 0; rr < 4; ++rr) {
        const float2 p0 = *(const float2*)&c1s[ic][2 * ty + rr][2 * tx];
        const float2 p1 = *(const float2*)&c1s[ic][2 * ty + rr][2 * tx + 2];
        cr[ic][rr][0] = p0.x; cr[ic][rr][1] = p0.y;
        cr[ic][rr][2] = p1.x; cr[ic][rr][3] = p1.y;
      }
    float m0 = -INFINITY, m1 = -INFINITY;
    #pragma unroll
    for (int sy = 0; sy < 2; ++sy)
      #pragma unroll
      for (int sx = 0; sx < 2; ++sx) {
        float a0 = B2[0], a1 = B2[1];
        #pragma unroll
        for (int ic = 0; ic < 3; ++ic)
          #pragma unroll
          for (int dy = 0; dy < 3; ++dy)
            #pragma unroll
            for (int dx = 0; dx < 3; ++dx) {
              const float v = cr[ic][sy + dy][sx + dx];
              a0 += v * W2[ic * 9 + dy * 3 + dx];
              a1 += v * W2[27 + ic * 9 + dy * 3 + dx];
            }
        m0 = fmaxf(m0, a0);
        m1 = fmaxf(m1, a1);
      }
    const size_t o = (size_t)(by * 15 + ty) * H2D + (bx * 15 + tx);
    h2[o] = m0;
    h2[(size_t)H2D * H2D + o] = m1;
  }
}

// ============ K3: rpn_conv (50x50, stride 50)  (reduced -> y [2,21,21]) ============
__global__ __launch_bounds__(256) void k3_rpnconv(
    const float* __restrict__ red,
    const float* __restrict__ w, const float* __restrict__ b,
    float* __restrict__ y) {
  __shared__ float part[256];
  const int cell = blockIdx.x;
  const int i = cell / FF, j = cell % FF;
  const int tid = threadIdx.x;
  float a0 = 0.f, a1 = 0.f;
  for (int t = tid; t < 2500; t += 256) {
    int ay = t / 50, ax = t % 50;
    float v = red[(size_t)(50 * i + ay) * FMD + 50 * j + ax];
    a0 += v * w[t];
    a1 += v * w[2500 + t];
  }
  part[tid] = a0;
  __syncthreads();
  for (int s = 128; s > 0; s >>= 1) {
    if (tid < s) part[tid] += part[tid + s];
    __syncthreads();
  }
  if (tid == 0) y[cell] = part[0] + b[0];
  __syncthreads();
  part[tid] = a1;
  __syncthreads();
  for (int s = 128; s > 0; s >>= 1) {
    if (tid < s) part[tid] += part[tid + s];
    __syncthreads();
  }
  if (tid == 0) y[441 + cell] = part[0] + b[1];
}

// ============ K4: rpn heads + faithful masked-select + proposals/rects ============
__global__ __launch_bounds__(512) void k4_select(
    const float* __restrict__ y,
    const float* __restrict__ bbw, const float* __restrict__ bbb,
    const float* __restrict__ clw, const float* __restrict__ clb,
    float* __restrict__ props_out, int* __restrict__ rects,
    unsigned* __restrict__ pooled_m) {
  __shared__ float ys[2][23][23];
  __shared__ unsigned char flag[6][441];
  __shared__ short pos[6][20];
  __shared__ int cnt[6];
  __shared__ int selT[20];
  __shared__ float offv[20], anchv[20];
  const int tid = threadIdx.x;
  for (int l = tid; l < 2 * 23 * 23; l += 512) ((float*)ys)[l] = 0.f;
  __syncthreads();
  for (int l = tid; l < 2 * 441; l += 512) {
    int c = l / 441, p = l % 441;
    ys[c][p / 21 + 1][p % 21 + 1] = y[l];
  }
  __syncthreads();
  for (int l = tid; l < 6 * 441; l += 512) {
    int a = l / 441, p = l % 441, i = p / 21, j = p % 21;
    float v = clb[a];
    #pragma unroll
    for (int c2 = 0; c2 < 2; c2++)
      #pragma unroll
      for (int dy = 0; dy < 3; dy++)
        #pragma unroll
        for (int dx = 0; dx < 3; dx++)
          v += ys[c2][i + dy][j + dx] * clw[a * 18 + c2 * 9 + dy * 3 + dx];
    flag[a][p] = (tanhf(v) > 0.95f) ? 1 : 0;
  }
  __syncthreads();
  if (tid < 6) {
    int c = 0;
    for (int p = 0; p < 441; p++)
      if (flag[tid][p]) {
        if (c < 20) pos[tid][c] = (short)p;
        c++;
      }
    cnt[tid] = c;
  }
  __syncthreads();
  if (tid == 0) {
    int s = 0;
    for (int g = 0; g < 24 && s < 20; g++) {
      int a = g >> 2;
      int take = cnt[a] < 20 - s ? cnt[a] : 20 - s;
      for (int r = 0; r < take; r++) selT[s++] = g * 441 + (int)pos[a][r];
    }
    if (s < 20) {
      for (int t = 0; t < 10584 && s < 20; t++) {
        int a = t / 1764, p = t % 441;
        if (!flag[a][p]) selT[s++] = t;
      }
    }
  }
  __syncthreads();
  if (tid < 20) {
    int t = selT[tid];
    int ch = t / 441, p = t % 441, i = p / 21, j = p % 21;
    int a = ch >> 2, c = ch & 3;
    float v = bbb[ch];
    #pragma unroll
    for (int c2 = 0; c2 < 2; c2++)
      #pragma unroll
      for (int dy = 0; dy < 3; dy++)
        #pragma unroll
        for (int dx = 0; dx < 3; dx++)
          v += ys[c2][i + dy][j + dx] * bbw[ch * 18 + c2 * 9 + dy * 3 + dx];
    offv[tid] = v;
    float sz = (a < 3) ? 1.f : 2.f;
    int am = a % 3;
    float ar = (am == 0) ? 0.5f : (am == 1 ? 1.f : 2.f);
    float base;
    if (c == 0) base = 0.f;
    else if (c == 1) base = sz * -(ar - 1.f) * 0.5f;
    else if (c == 2) base = sz;
    else base = sz * (1.f + (ar - 1.f) * 0.5f);
    anchv[tid] = base + ((c & 1) ? (float)j : (float)i);
  }
  __syncthreads();
  if (tid < 5) {
    int k = tid;
    float o0 = offv[4 * k], o1 = offv[4 * k + 1], o2 = offv[4 * k + 2], o3 = offv[4 * k + 3];
    float a0 = anchv[4 * k], a2 = anchv[4 * k + 2], a3 = anchv[4 * k + 3];
    float p0 = fminf(fmaxf(o0 + a0 - a2 * 0.5f, 0.f), 21.f) * 50.f;
    float p1 = fminf(fmaxf(o1 - a3 * 0.5f, 0.f), 21.f) * 50.f;
    float p2 = fminf(fmaxf(o2 + a0 + a2 * 0.5f, 0.f), 21.f) * 50.f;
    float p3 = fminf(fmaxf(o3 + a3 * 0.5f, 0.f), 21.f) * 50.f;
    props_out[k * 4 + 0] = p0;
    props_out[k * 4 + 1] = p1;
    props_out[k * 4 + 2] = p2;
    props_out[k * 4 + 3] = p3;
    float x1 = rintf(p0), y1 = rintf(p1), x2 = rintf(p2), y2 = rintf(p3);
    float bwf = fmaxf(x2 - x1 + 1.f, 1.f) * 0.5f;
    float bhf = fmaxf(y2 - y1 + 1.f, 1.f) * 0.5f;
    for (int ph = 0; ph < 2; ph++)
      for (int pw = 0; pw < 2; pw++) {
        int hsv = (int)fminf(fmaxf(floorf((float)ph * bhf) + y1, 0.f), 1080.f);
        int hev = (int)fminf(fmaxf(ceilf((float)(ph + 1) * bhf) + y1, 0.f), 1080.f);
        int wsv = (int)fminf(fmaxf(floorf((float)pw * bwf) + x1, 0.f), 1080.f);
        int wev = (int)fminf(fmaxf(ceilf((float)(pw + 1) * bwf) + x1, 0.f), 1080.f);
        int idx = k * 4 + ph * 2 + pw;
        rects[idx * 4 + 0] = hsv;
        rects[idx * 4 + 1] = hev;
        rects[idx * 4 + 2] = wsv;
        rects[idx * 4 + 3] = wev;
      }
  }
  if (tid >= 32 && tid < 52) pooled_m[tid - 32] = 0x007FFFFFu;  // mapped(-inf)
}

// ============ K5: RoI max pool (atomicMax on order-preserving uint map) ============
__global__ __launch_bounds__(256) void k5_roipool(
    const float* __restrict__ red, const int* __restrict__ rects,
    unsigned* __restrict__ pooled_m) {
  const int cell = blockIdx.x;
  const int hs = rects[cell * 4 + 0], he = rects[cell * 4 + 1];
  const int wss = rects[cell * 4 + 2], wee = rects[cell * 4 + 3];
  const int nr = he - hs;
  if (nr <= 0 || wee <= wss) return;
  const int slice = blockIdx.y, nslice = gridDim.y;
  const int r0 = hs + (int)((long)nr * slice / nslice);
  const int r1 = hs + (int)((long)nr * (slice + 1) / nslice);
  float m = -INFINITY;
  for (int r = r0; r < r1; r++)
    for (int c = wss + (int)threadIdx.x; c < wee; c += 256)
      m = fmaxf(m, red[(size_t)r * FMD + c]);
  __shared__ float part[256];
  part[threadIdx.x] = m;
  __syncthreads();
  for (int s = 128; s > 0; s >>= 1) {
    if ((int)threadIdx.x < s) part[threadIdx.x] = fmaxf(part[threadIdx.x], part[threadIdx.x + s]);
    __syncthreads();
  }
  if (threadIdx.x == 0 && part[0] > -INFINITY) {
    unsigned u = __float_as_uint(part[0]);
    u = (u & 0x80000000u) ? ~u : (u | 0x80000000u);
    atomicMax(&pooled_m[cell], u);
  }
}

// ============ K6: fc / box / cls heads -> d_out (30 floats) ============
__global__ void k6_heads(
    const unsigned* __restrict__ pooled_m, const float* __restrict__ props,
    const float* __restrict__ fcw, const float* __restrict__ fcb,
    const float* __restrict__ bxw, const float* __restrict__ bxb,
    const float* __restrict__ clw, const float* __restrict__ clb,
    float* __restrict__ out) {
  if (threadIdx.x != 0 || blockIdx.x != 0) return;
  float pooled[5][4];
  for (int i = 0; i < 20; i++) {
    unsigned u = pooled_m[i];
    float f = (u & 0x80000000u) ? __uint_as_float(u ^ 0x80000000u) : __uint_as_float(~u);
    if (!isfinite(f)) f = 0.f;
    pooled[i / 4][i % 4] = f;
  }
  for (int k = 0; k < 5; k++) {
    float fc[12];
    for (int m = 0; m < 12; m++) {
      float v = fcb[m];
      for (int n = 0; n < 4; n++) v += pooled[k][n] * fcw[m * 4 + n];
      fc[m] = v;
    }
    float bo[4];
    for (int c = 0; c < 4; c++) {
      float v = bxb[c];
      for (int m = 0; m < 12; m++) v += fc[m] * bxw[c * 12 + m];
      bo[c] = v;
    }
    float p0 = props[k * 4], p1 = props[k * 4 + 1], p2 = props[k * 4 + 2], p3 = props[k * 4 + 3];
    out[k * 4 + 0] = fminf(fmaxf(p0 + bo[0] - bo[2] * 0.5f, 0.f), 3.f);
    out[k * 4 + 1] = fminf(fmaxf(p1 - bo[3] * 0.5f, 0.f), 1.f);
    out[k * 4 + 2] = fminf(fmaxf(p2 + bo[0] + bo[2] * 0.5f, 0.f), 3.f);
    out[k * 4 + 3] = fminf(fmaxf(p3 + bo[3] * 0.5f, 0.f), 1.f);
    float l0 = clb[0], l1 = clb[1];
    for (int m = 0; m < 12; m++) {
      l0 += fc[m] * clw[m];
      l1 += fc[m] * clw[12 + m];
    }
    float mx = fmaxf(l0, l1);
    float e0 = expf(l0 - mx), e1 = expf(l1 - mx);
    out[20 + k * 2 + 0] = e0 / (e0 + e1);
    out[20 + k * 2 + 1] = e1 / (e0 + e1);
  }
}

extern "C" void kernel_launch(void* const* d_in, const int* in_sizes, int n_in,
                              void* d_out, int out_size, void* d_ws, size_t ws_size,
                              hipStream_t stream) {
  const float* x   = (const float*)d_in[0];
  const float* w1  = (const float*)d_in[1];
  const float* b1  = (const float*)d_in[2];
  const float* w2  = (const float*)d_in[3];
  const float* b2  = (const float*)d_in[4];
  const float* w3  = (const float*)d_in[5];
  const float* b3  = (const float*)d_in[6];
  const float* w4  = (const float*)d_in[7];
  const float* b4  = (const float*)d_in[8];
  const float* rw  = (const float*)d_in[9];
  const float* rb  = (const float*)d_in[10];
  const float* bbw = (const float*)d_in[11];
  const float* bbb = (const float*)d_in[12];
  const float* clw = (const float*)d_in[13];
  const float* clb = (const float*)d_in[14];
  const float* fcw = (const float*)d_in[15];
  const float* fcb = (const float*)d_in[16];
  const float* bxw = (const float*)d_in[17];
  const float* bxb = (const float*)d_in[18];
  const float* c2w = (const float*)d_in[19];
  const float* c2b = (const float*)d_in[20];

  char* wsb = (char*)d_ws;

  if (ws_size >= 160000000ull) {
    // split path: c1(bf16) | h2 | red | small
    u16*   c1u = (u16*)wsb;
    float* h2  = (float*)(wsb + 111974400);
    float* red = (float*)(wsb + 149299200);
    float* yv  = (float*)(wsb + 153964800);
    float* props = yv + 882;
    int*   rects = (int*)(props + 20);
    unsigned* pooled_m = (unsigned*)(rects + 80);

    k_conv1    <<<4557, 256, 0, stream>>>(x, w1, b1, c1u);
    k_conv2pool<<<4557, 256, 0, stream>>>(c1u, w2, b2, h2);
    k2_backbone2<<<dim3(72, 72), 256, 0, stream>>>(h2, w3, b3, w4, b4, red);
    k3_rpnconv<<<441, 256, 0, stream>>>(red, rw, rb, yv);
    k4_select<<<1, 512, 0, stream>>>(yv, bbw, bbb, clw, clb, props, rects, pooled_m);
    k5_roipool<<<dim3(20, 16), 256, 0, stream>>>(red, rects, pooled_m);
    k6_heads<<<1, 64, 0, stream>>>(pooled_m, props, fcw, fcb, bxw, bxb, c2w, c2b,
                                   (float*)d_out);
  } else {
    // fallback: round-2 fused path (42 MB workspace)
    float* ws = (float*)d_ws;
    float* h2 = ws;
    float* red = ws + 9331200;
    float* yv = ws + 10497600;
    float* props = ws + 10498482;
    int* rects = (int*)(ws + 10498502);
    unsigned* pooled_m = (unsigned*)(ws + 10498582);

    k1_backbone1<<<dim3(144, 144), 256, 0, stream>>>(x, w1, b1, w2, b2, h2);
    k2_backbone2<<<dim3(72, 72), 256, 0, stream>>>(h2, w3, b3, w4, b4, red);
    k3_rpnconv<<<441, 256, 0, stream>>>(red, rw, rb, yv);
    k4_select<<<1, 512, 0, stream>>>(yv, bbw, bbb, clw, clb, props, rects, pooled_m);
    k5_roipool<<<dim3(20, 16), 256, 0, stream>>>(red, rects, pooled_m);
    k6_heads<<<1, 64, 0, stream>>>(pooled_m, props, fcw, fcb, bxw, bxb, c2w, c2b,
                                   (float*)d_out);
  }
}